// Round 16
// baseline (731.919 us; speedup 1.0000x reference)
//
#include <hip/hip_runtime.h>
#include <hip/hip_bf16.h>
#include <math.h>

#define B_ 16
#define C_ 512
#define T_ 4096
#define I_ 1536

typedef short short8 __attribute__((ext_vector_type(8)));
typedef unsigned short ushort8 __attribute__((ext_vector_type(8)));
typedef unsigned short us4 __attribute__((ext_vector_type(4)));
typedef float f32x4 __attribute__((ext_vector_type(4)));
typedef int i32x4 __attribute__((ext_vector_type(4)));
typedef char char8v __attribute__((ext_vector_type(8)));

static __device__ __forceinline__ unsigned short f2bf(float f) {
  union { float f; unsigned int u; } v; v.f = f;
  unsigned int r = v.u + 0x7fffu + ((v.u >> 16) & 1u);
  return (unsigned short)(r >> 16);
}
static __device__ __forceinline__ float bf2f(unsigned short h) {
  union { unsigned int u; float f; } v; v.u = ((unsigned int)h) << 16;
  return v.f;
}

static __device__ __forceinline__ float fast_rcp(float x) {
  float r; asm("v_rcp_f32 %0, %1" : "=v"(r) : "v"(x)); return r;
}

// tanh-form GELU. |err vs erf| <= ~3e-3/elem, diluted by @W2.
static __device__ __forceinline__ float gelu_f(float v) {
  const float v2 = v * v;
  const float w = v * (0.7978845608f + 0.0356774081f * v2);
  const float a = fminf(w * 2.8853900818f, 126.0f);
  const float u = exp2f(a);
  return v * u * fast_rcp(u + 1.0f);
}

static __device__ __forceinline__ int q8i(float v, float inv) {
  int q = __float2int_rn(v * inv);
  q = q > 127 ? 127 : (q < -127 ? -127 : q);
  return q;
}
static __device__ __forceinline__ char q8(float v, float inv) {
  return (char)q8i(v, inv);
}

__device__ __forceinline__ void gload_lds16(const void* g, void* l) {
  __builtin_amdgcn_global_load_lds((const __attribute__((address_space(1))) void*)g,
                                   (__attribute__((address_space(3))) void*)l, 16, 0, 0);
}

#define H1S   (3.0f / 127.0f)
#define IH1S  (127.0f / 3.0f)

// kappa within each 128-block: k -> c : wcbit=k>>6, lrow=(k&63)>>2, nf=k&3, c=wcbit*64+nf*16+lrow
// c -> k : kappa(c) = (c>>6)*64 + (c&15)*4 + ((c&63)>>4)
static __device__ __forceinline__ int kappa_to_c(int k128) {
  const int wcbit = k128 >> 6, lrow = (k128 & 63) >> 2, n = k128 & 3;
  return wcbit * 64 + n * 16 + lrow;
}
static __device__ __forceinline__ int c_to_kappa(int c128) {
  return (c128 >> 6) * 64 + (c128 & 15) * 4 + ((c128 & 63) >> 4);
}

// ---------------- precompute stage A: kv + weight scales ----------------
// bid<256: kv (4-accumulator ILP). bid 256..279: W1 scale tiles (64 cols each).
// bid 280..287: W2 scale tiles. Coalesced 256B reads + LDS atomicMax reduce.

__global__ __launch_bounds__(256) void pre_a(const float* __restrict__ aux,
                                             const float* __restrict__ Wkv,
                                             const float* __restrict__ bkv,
                                             const float* __restrict__ W1,
                                             const float* __restrict__ W2,
                                             float* __restrict__ kv,
                                             float* __restrict__ w1s,
                                             float* __restrict__ w2s) {
  __shared__ unsigned int red64[64];
  const int bid = blockIdx.x;
  const int tid = threadIdx.x;
  if (bid < 256) {
    const int g = bid * 256 + tid;              // 65536 = 64 * 1024
    const int j = g >> 10, cc = g & 1023;
    float s0 = 0.f, s1 = 0.f, s2 = 0.f, s3 = 0.f;
    for (int i = 0; i < C_; i += 4) {
      s0 = fmaf(aux[j * C_ + i + 0], Wkv[(size_t)(i + 0) * 1024 + cc], s0);
      s1 = fmaf(aux[j * C_ + i + 1], Wkv[(size_t)(i + 1) * 1024 + cc], s1);
      s2 = fmaf(aux[j * C_ + i + 2], Wkv[(size_t)(i + 2) * 1024 + cc], s2);
      s3 = fmaf(aux[j * C_ + i + 3], Wkv[(size_t)(i + 3) * 1024 + cc], s3);
    }
    kv[g] = bkv[cc] + ((s0 + s1) + (s2 + s3));
    return;
  }
  const bool isW1 = bid < 280;
  const int n0 = isW1 ? (bid - 256) * 64 : (bid - 280) * 64;
  const int ROWS = isW1 ? 512 : 1536;
  const int NC   = isW1 ? 1536 : 512;
  const float* W = isW1 ? W1 : W2;
  if (tid < 64) red64[tid] = 0;
  __syncthreads();
  const int noff = tid & 63, ks = tid >> 6;     // 4 k-slices
  float amax = 0.f;
#pragma unroll 4
  for (int k = ks; k < ROWS; k += 4)
    amax = fmaxf(amax, fabsf(W[(size_t)k * NC + n0 + noff]));
  atomicMax(&red64[noff], __float_as_uint(amax));
  __syncthreads();
  if (tid < 64)
    (isW1 ? w1s : w2s)[n0 + tid] = fmaxf(__uint_as_float(red64[tid]), 1e-20f) / 127.0f;
}

// ---------------- precompute stage B: MT, cb, VoT(kappa) ----------------

__global__ __launch_bounds__(256) void pre_b(const float* __restrict__ Wq,
                                             const float* __restrict__ bq,
                                             const float* __restrict__ Wo,
                                             const float* __restrict__ kv,
                                             unsigned short* __restrict__ MT,
                                             float* __restrict__ cbias,
                                             unsigned short* __restrict__ VoT) {
  const int bid = blockIdx.x;
  const int tid = threadIdx.x;
  if (bid < 512) {
    const int col = bid;
    const int h = col >> 6, j = col & 63;
    const float* kvp = kv + j * 1024 + h * 64;
    for (int c = tid; c < C_; c += 256) {
      float s = 0.f;
#pragma unroll 8
      for (int d = 0; d < 64; ++d) s += Wq[(size_t)c * C_ + h * 64 + d] * kvp[d];
      MT[(size_t)col * C_ + c] = f2bf(0.125f * s);
    }
    if (tid == 0) {
      float s = 0.f;
      for (int d = 0; d < 64; ++d) s += bq[h * 64 + d] * kvp[d];
      cbias[col] = 0.125f * s;
    }
  } else {
    const int cp = bid - 512;
    for (int k = tid; k < 512; k += 256) {
      const int c = (k >> 7) * 128 + kappa_to_c(k & 127);   // true attention col
      const int h = c >> 6, j = c & 63;
      float s = 0.f;
#pragma unroll 8
      for (int d = 0; d < 64; ++d)
        s += kv[j * 1024 + 512 + h * 64 + d] * Wo[(size_t)(h * 64 + d) * C_ + cp];
      VoT[(size_t)cp * 512 + k] = f2bf(s);
    }
  }
}

// ---------------- precompute stage W: coalesced transpose-quantize of W1/W2 ----------------
// bid<96: W1 tiles (64n x 128k). bid 96..191: W2 tiles (64n x 128k, kappa in-LDS).

__global__ __launch_bounds__(256) void pre_w(const float* __restrict__ W1,
                                             const float* __restrict__ W2,
                                             const float* __restrict__ w1s,
                                             const float* __restrict__ w2s,
                                             char* __restrict__ W1Q,
                                             char* __restrict__ W2Q) {
  __shared__ char tile[64][144];
  __shared__ float invs[64];
  const int bid = blockIdx.x, tid = threadIdx.x;
  const bool isW1 = bid < 96;
  int n0, k0;
  if (isW1) { const int tw = bid;      n0 = (tw >> 2) * 64; k0 = (tw & 3) * 128; }
  else      { const int tw = bid - 96; n0 = (tw / 12) * 64; k0 = (tw % 12) * 128; }
  if (tid < 64) invs[tid] = 1.0f / (isW1 ? w1s[n0 + tid] : w2s[n0 + tid]);
  __syncthreads();
#pragma unroll
  for (int s = 0; s < 32; ++s) {
    const int f = s * 256 + tid;        // 8192 = 128 rows x 64 n
    const int r = f >> 6, n = f & 63;
    if (isW1) {
      tile[n][r] = q8(W1[(size_t)(k0 + r) * 1536 + n0 + n], invs[n]);
    } else {
      tile[n][c_to_kappa(r)] = q8(W2[(size_t)(k0 + r) * 512 + n0 + n], invs[n]);
    }
  }
  __syncthreads();
#pragma unroll
  for (int s = 0; s < 2; ++s) {
    const int idx = s * 256 + tid;      // 512 char16s
    const int n = idx >> 3, kc = idx & 7;
    const i32x4 v = *(const i32x4*)&tile[n][kc * 16];
    if (isW1) *(i32x4*)&W1Q[(size_t)(n0 + n) * 512 + k0 + kc * 16] = v;
    else      *(i32x4*)&W2Q[(size_t)(n0 + n) * 1536 + k0 + kc * 16] = v;
  }
}

// ---------------- x (B,C,T) -> xt bf16 (B*T, C), vectorized stores ----------------

__global__ __launch_bounds__(256) void xt_kernel(const float* __restrict__ x,
                                                 unsigned short* __restrict__ xt) {
  __shared__ float ld[64][65];
  const int tid = threadIdx.x;
  const int t0 = blockIdx.x * 64, c0 = blockIdx.y * 64, b = blockIdx.z;
  for (int idx = tid; idx < 4096; idx += 256) {
    const int r = idx >> 6, cc = idx & 63;
    ld[r][cc] = x[((size_t)(b * C_ + c0 + r)) * T_ + t0 + cc];
  }
  __syncthreads();
#pragma unroll
  for (int s = 0; s < 2; ++s) {
    const int idx = s * 256 + tid;      // 512 = 64 t-rows x 8 col-chunks
    const int tr = idx >> 3, cl8 = (idx & 7) * 8;
    ushort8 o;
#pragma unroll
    for (int qv = 0; qv < 8; ++qv) o[qv] = f2bf(ld[cl8 + qv][tr]);
    *(ushort8*)&xt[((size_t)(b * T_ + t0 + tr)) * C_ + c0 + cl8] = o;
  }
}

// ---------------- GEMM A (m97 structure): attention GEMMs ----------------
// EPI 1: softmax epilogue, P stored kappa-packed (ushort4 per (m,i)).
// EPI 4: LDS-bounce [c][t] bf16 tile -> coalesced full-row ushort8 stores of rs.
template<int N, int K, int NCOL, int EPI>
__global__ __launch_bounds__(256) void gemm_mfma(const unsigned short* __restrict__ A,
                                                 const unsigned short* __restrict__ Bt,
                                                 const float* __restrict__ bias,
                                                 unsigned short* __restrict__ outU,
                                                 const unsigned short* __restrict__ resU,
                                                 float* __restrict__ outF) {
  __shared__ __align__(16) unsigned short lA[128 * 32];
  __shared__ __align__(16) unsigned short lB[128 * 32];
  __shared__ __align__(16) unsigned short bounce[EPI == 4 ? 128 * 132 : 8];
  const int q = gridDim.x >> 3;
  const int wgid = (blockIdx.x & 7) * q + (blockIdx.x >> 3);
  const int row0 = (wgid / NCOL) * 128;
  const int col0 = (wgid % NCOL) * 128;
  const int tid = threadIdx.x;
  const int w = tid >> 6, lane = tid & 63;
  const int wr = (w >> 1) * 64, wc = (w & 1) * 64;
  const int c1 = tid, c2 = tid + 256;

  const f32x4 zero4 = {0.f, 0.f, 0.f, 0.f};
  f32x4 acc[4][4];
#pragma unroll
  for (int m = 0; m < 4; ++m)
#pragma unroll
    for (int n = 0; n < 4; ++n) acc[m][n] = zero4;

  const size_t aBase = (size_t)row0 * K;
  const size_t bBase = (size_t)col0 * K;
  const int lrow = lane & 15, lg = lane >> 4;

  for (int k0 = 0; k0 < K; k0 += 32) {
    gload_lds16(A + aBase + (size_t)(c1 & 127) * K + k0 + (c1 >> 7) * 8, (char*)lA + c1 * 16);
    gload_lds16(A + aBase + (size_t)(c2 & 127) * K + k0 + (c2 >> 7) * 8, (char*)lA + c2 * 16);
    gload_lds16(Bt + bBase + (size_t)(c1 & 127) * K + k0 + (c1 >> 7) * 8, (char*)lB + c1 * 16);
    gload_lds16(Bt + bBase + (size_t)(c2 & 127) * K + k0 + (c2 >> 7) * 8, (char*)lB + c2 * 16);
    __syncthreads();
    short8 av[4], bv[4];
#pragma unroll
    for (int m = 0; m < 4; ++m)
      av[m] = *(const short8*)&lA[(lg * 128 + wr + m * 16 + lrow) * 8];
#pragma unroll
    for (int n = 0; n < 4; ++n)
      bv[n] = *(const short8*)&lB[(lg * 128 + wc + n * 16 + lrow) * 8];
#pragma unroll
    for (int m = 0; m < 4; ++m)
#pragma unroll
      for (int n = 0; n < 4; ++n)
        acc[m][n] = __builtin_amdgcn_mfma_f32_16x16x32_bf16(av[m], bv[n], acc[m][n], 0, 0, 0);
    __syncthreads();
  }

  if (EPI == 1) {
    float cbv[4];
#pragma unroll
    for (int n = 0; n < 4; ++n) cbv[n] = bias[col0 + wc + n * 16 + lrow];
    const int kbase = col0 + wc + lrow * 4;     // kappa address of this thread's 4 cols
#pragma unroll
    for (int m = 0; m < 4; ++m) {
#pragma unroll
      for (int i = 0; i < 4; ++i) {
        float e0 = acc[m][0][i] + cbv[0];
        float e1 = acc[m][1][i] + cbv[1];
        float e2 = acc[m][2][i] + cbv[2];
        float e3 = acc[m][3][i] + cbv[3];
        float mx = fmaxf(fmaxf(e0, e1), fmaxf(e2, e3));
        mx = fmaxf(mx, __shfl_xor(mx, 1));
        mx = fmaxf(mx, __shfl_xor(mx, 2));
        mx = fmaxf(mx, __shfl_xor(mx, 4));
        mx = fmaxf(mx, __shfl_xor(mx, 8));
        e0 = __expf(e0 - mx); e1 = __expf(e1 - mx);
        e2 = __expf(e2 - mx); e3 = __expf(e3 - mx);
        float s = e0 + e1 + e2 + e3;
        s += __shfl_xor(s, 1);
        s += __shfl_xor(s, 2);
        s += __shfl_xor(s, 4);
        s += __shfl_xor(s, 8);
        const float inv = 1.0f / s;
        us4 pk;
        pk[0] = f2bf(e0 * inv); pk[1] = f2bf(e1 * inv);
        pk[2] = f2bf(e2 * inv); pk[3] = f2bf(e3 * inv);
        *(us4*)&outU[(size_t)(row0 + wr + m * 16 + lg * 4 + i) * N + kbase] = pk;
      }
    }
    return;
  }

  // EPI == 4 : residual epilogue with LDS transpose bounce
#pragma unroll
  for (int m = 0; m < 4; ++m) {
    const int r0 = row0 + wr + m * 16 + (lg << 2);
    const int tl = wr + m * 16 + (lg << 2);
#pragma unroll
    for (int n = 0; n < 4; ++n) {
      const int cl = wc + n * 16 + lrow;
      const int c = col0 + cl;
      const float bb = bias[c];
      us4 pk;
#pragma unroll
      for (int i = 0; i < 4; ++i)
        pk[i] = f2bf(bf2f(resU[(size_t)(r0 + i) * 512 + c]) + acc[m][n][i] + bb);
      *(us4*)&bounce[cl * 132 + tl] = pk;
    }
  }
  __syncthreads();
  const int bidx = row0 >> 12;
  const int t0 = row0 & 4095;
#pragma unroll
  for (int j = 0; j < 8; ++j) {
    const int cl = j * 16 + w * 4 + (lane >> 4);
    const int t = (lane & 15) * 8;
    const ushort8 v = *(const ushort8*)&bounce[cl * 132 + t];
    *(ushort8*)&outU[((size_t)(bidx * C_ + col0 + cl)) * T_ + t0 + t] = v;
  }
}

// ---------------- GEMM B: int8, 8 waves, 128x256 tile, BK=64, 3-buf ----------------
// EPI 3: kappa-packed char4 stores of H1Q. EPI 5: 2-pass LDS-bounce coalesced f32 stores.
template<int N, int K, int NCOL, int EPI>
__global__ __launch_bounds__(512, 4) void gemm8w(const char* __restrict__ A,
                                                 const char* __restrict__ Bt,
                                                 const float* __restrict__ rowS,
                                                 const float* __restrict__ colS,
                                                 const float* __restrict__ bias,
                                                 char* __restrict__ outQ,
                                                 const unsigned short* __restrict__ resU,
                                                 float* __restrict__ outF) {
  __shared__ __align__(16) char lds[73728];
  const int tid = threadIdx.x;
  const int w = tid >> 6, lane = tid & 63;
  const int wm = w >> 2, wn = w & 3;            // 2x4 wave grid
  const int lrow = lane & 15, lg = lane >> 4;
  const int q8g = gridDim.x >> 3;
  const int wgid = (blockIdx.x & 7) * q8g + (blockIdx.x >> 3);
  const int row0 = (wgid / NCOL) * 128;
  const int col0 = (wgid % NCOL) * 128 * 2;     // BN=256

  auto stageA = [&](int kt, int b) {
    gload_lds16(A + (size_t)(row0 + (tid & 127)) * K + kt * 64 + (tid >> 7) * 16,
                lds + b * 8192 + tid * 16);
  };
  auto stageB = [&](int kt, int b) {
#pragma unroll
    for (int s = 0; s < 2; ++s) {
      const int q = s * 512 + tid;
      gload_lds16(Bt + (size_t)(col0 + (q & 255)) * K + kt * 64 + (q >> 8) * 16,
                  lds + 24576 + b * 16384 + q * 16);
    }
  };

  const i32x4 zero4 = {0, 0, 0, 0};
  i32x4 acc[4][4];
#pragma unroll
  for (int m = 0; m < 4; ++m)
#pragma unroll
    for (int n = 0; n < 4; ++n) acc[m][n] = zero4;

  const int KT = K / 64;     // G3: 8, G4: 24

  stageA(0, 0); stageB(0, 0);
  stageA(1, 1); stageB(1, 1);
  asm volatile("s_waitcnt vmcnt(3)" ::: "memory");
  __builtin_amdgcn_s_barrier();

  int cur = 0;
  for (int t = 0; t < KT; ++t) {
    if (t + 2 < KT) {
      const int nb = (cur + 2 >= 3) ? cur - 1 : cur + 2;
      stageA(t + 2, nb); stageB(t + 2, nb);
    }
    const char* ab = lds + cur * 8192;
    const char* bb = lds + 24576 + cur * 16384;
    i32x4 av[4], bv[4];
#pragma unroll
    for (int mf = 0; mf < 4; ++mf)
      av[mf] = *(const i32x4*)(ab + (size_t)(lg * 128 + wm * 64 + mf * 16 + lrow) * 16);
#pragma unroll
    for (int nf = 0; nf < 4; ++nf)
      bv[nf] = *(const i32x4*)(bb + (size_t)(lg * 256 + wn * 64 + nf * 16 + lrow) * 16);
    __builtin_amdgcn_s_setprio(1);
#pragma unroll
    for (int mf = 0; mf < 4; ++mf)
#pragma unroll
      for (int nf = 0; nf < 4; ++nf)
        acc[mf][nf] = __builtin_amdgcn_mfma_i32_16x16x64_i8(av[mf], bv[nf],
                                                            acc[mf][nf], 0, 0, 0);
    __builtin_amdgcn_s_setprio(0);
    if (t + 2 < KT) { asm volatile("s_waitcnt vmcnt(3)" ::: "memory"); }
    else            { asm volatile("s_waitcnt vmcnt(0)" ::: "memory"); }
    __builtin_amdgcn_s_barrier();
    cur = (cur == 2) ? 0 : cur + 1;
  }

  if (EPI == 3) {
    const int kbase = col0 + (wn >> 1) * 128 + (wn & 1) * 64 + lrow * 4;
#pragma unroll
    for (int mf = 0; mf < 4; ++mf) {
      const int r0 = row0 + wm * 64 + mf * 16 + lg * 4;
      float rs4[4];
#pragma unroll
      for (int i = 0; i < 4; ++i) rs4[i] = rowS[r0 + i];
      float dsv[4], bbv[4];
#pragma unroll
      for (int nf = 0; nf < 4; ++nf) {
        const int c = col0 + wn * 64 + nf * 16 + lrow;
        dsv[nf] = colS[c];
        bbv[nf] = bias[c];
      }
#pragma unroll
      for (int i = 0; i < 4; ++i) {
        unsigned int pk = 0;
#pragma unroll
        for (int nf = 0; nf < 4; ++nf) {
          const float v = fmaf((float)acc[mf][nf][i], rs4[i] * dsv[nf], bbv[nf]);
          const float g = gelu_f(v);
          const unsigned int b =
              (unsigned int)(unsigned char)(char)q8i(fminf(fmaxf(g, -3.0f), 3.0f), IH1S);
          pk |= b << (8 * nf);
        }
        *(unsigned int*)&outQ[(size_t)(r0 + i) * N + kbase] = pk;
      }
    }
    return;
  }

  // EPI == 5 : 2-pass LDS bounce (128c x 128t f32, stride 132) -> coalesced stores
  float* fb = (float*)lds;
  const int bidx = row0 >> 12;
  const int t0 = row0 & 4095;
#pragma unroll
  for (int p = 0; p < 2; ++p) {
    if ((wn >> 1) == p) {
#pragma unroll
      for (int mf = 0; mf < 4; ++mf) {
        const int tl = wm * 64 + mf * 16 + lg * 4;
#pragma unroll
        for (int nf = 0; nf < 4; ++nf) {
          const int cl = (wn & 1) * 64 + nf * 16 + lrow;
          const int c = col0 + p * 128 + cl;
          const float ds = H1S * colS[c];
          const float bb = bias[c];
          f32x4 v;
#pragma unroll
          for (int i = 0; i < 4; ++i) v[i] = fmaf((float)acc[mf][nf][i], ds, bb);
          *(f32x4*)&fb[cl * 132 + tl] = v;
        }
      }
    }
    __syncthreads();
#pragma unroll
    for (int j = 0; j < 8; ++j) {
      const int cl = j * 16 + w * 2 + (lane >> 5);
      const int t = (lane & 31) * 4;
      const f32x4 v = *(const f32x4*)&fb[cl * 132 + t];
      const size_t addr = ((size_t)(bidx * C_ + col0 + p * 128 + cl)) * T_ + t0 + t;
      const us4 rv = *(const us4*)&resU[addr];
      f32x4 o;
#pragma unroll
      for (int i = 0; i < 4; ++i) o[i] = v[i] + bf2f(rv[i]);
      *(f32x4*)&outF[addr] = o;
    }
    __syncthreads();
  }
}

// ---------------- fused conv1d(k=7,p=3) + AdaLayerNorm -> int8 yln + per-token scale ----------------
// rs window staged via LDS for coalesced reads (was lane-stride-8KB uncoalesced).

__global__ __launch_bounds__(256) void convq_kernel(
    const unsigned short* __restrict__ rs,
    const float* __restrict__ dww,
    const float* __restrict__ dwb,
    const int* __restrict__ ids,
    const float* __restrict__ sce,
    const float* __restrict__ she,
    char* __restrict__ ylnq,
    float* __restrict__ yscale) {
  __shared__ unsigned short rbuf[512 * 28];   // [c][24t + pad], bf16
  __shared__ float cbuf[16 * 520];
  const int tid = threadIdx.x;
  const int t0 = blockIdx.x * 16;
  const int b = blockIdx.y;
  // stage rs[c][t0-4 .. t0+19]
#pragma unroll
  for (int s = 0; s < 12; ++s) {
    const int f = s * 256 + tid;      // 3072 = 512c * 6 chunks of 4t
    const int c = f / 6, ch = f - c * 6;
    const int t = t0 - 4 + ch * 4;
    us4 v = {0, 0, 0, 0};
    if (t >= 0 && t < T_) v = *(const us4*)&rs[((size_t)(b * C_ + c)) * T_ + t];
    *(us4*)&rbuf[c * 28 + ch * 4] = v;
  }
  __syncthreads();
#pragma unroll
  for (int cc = 0; cc < 2; ++cc) {
    const int c = cc * 256 + tid;
    float f[24];
#pragma unroll
    for (int i = 0; i < 24; ++i) f[i] = bf2f(rbuf[c * 28 + i]);
    float wk[7];
#pragma unroll
    for (int k = 0; k < 7; ++k) wk[k] = dww[c * 7 + k];
    const float bb = dwb[c];
#pragma unroll
    for (int tt = 0; tt < 16; ++tt) {
      float s = bb;
#pragma unroll
      for (int k = 0; k < 7; ++k) s += f[tt + 1 + k] * wk[k];
      cbuf[tt * 520 + c] = s;
    }
  }
  __syncthreads();
  const int lane = tid & 63, w = tid >> 6;
  const int id = ids[b];
#pragma unroll
  for (int tt = 0; tt < 4; ++tt) {
    const int t = w * 4 + tt;
    const f32x4 v0 = *(const f32x4*)&cbuf[t * 520 + lane * 8];
    const f32x4 v1 = *(const f32x4*)&cbuf[t * 520 + lane * 8 + 4];
    float s = 0.f, sq = 0.f;
#pragma unroll
    for (int i = 0; i < 4; ++i) { s += v0[i]; sq += v0[i] * v0[i]; }
#pragma unroll
    for (int i = 0; i < 4; ++i) { s += v1[i]; sq += v1[i] * v1[i]; }
#pragma unroll
    for (int off = 1; off < 64; off <<= 1) {
      s += __shfl_xor(s, off);
      sq += __shfl_xor(sq, off);
    }
    const float mean = s * (1.0f / 512.0f);
    const float var = sq * (1.0f / 512.0f) - mean * mean;
    const float rstd = rsqrtf(var + 1e-6f);
    const f32x4 sc0 = *(const f32x4*)&sce[id * C_ + lane * 8];
    const f32x4 sc1 = *(const f32x4*)&sce[id * C_ + lane * 8 + 4];
    const f32x4 sh0 = *(const f32x4*)&she[id * C_ + lane * 8];
    const f32x4 sh1 = *(const f32x4*)&she[id * C_ + lane * 8 + 4];
    float y[8];
    float amax = 0.f;
#pragma unroll
    for (int i = 0; i < 4; ++i) {
      y[i]     = (v0[i] - mean) * rstd * sc0[i] + sh0[i];
      y[4 + i] = (v1[i] - mean) * rstd * sc1[i] + sh1[i];
    }
#pragma unroll
    for (int i = 0; i < 8; ++i) amax = fmaxf(amax, fabsf(y[i]));
#pragma unroll
    for (int off = 1; off < 64; off <<= 1) amax = fmaxf(amax, __shfl_xor(amax, off));
    amax = fmaxf(amax, 1e-20f);
    const float inv = 127.0f / amax;
    const int tg = b * T_ + t0 + t;
    char8v o;
#pragma unroll
    for (int i = 0; i < 8; ++i) o[i] = q8(y[i], inv);
    *(char8v*)&ylnq[(size_t)tg * C_ + lane * 8] = o;
    if (lane == 0) yscale[tg] = amax * (1.0f / 127.0f);
  }
}

// ---------------- launch ----------------

extern "C" void kernel_launch(void* const* d_in, const int* in_sizes, int n_in,
                              void* d_out, int out_size, void* d_ws, size_t ws_size,
                              hipStream_t stream) {
  const float* x   = (const float*)d_in[0];
  const int*   ids = (const int*)d_in[1];
  const float* Wq  = (const float*)d_in[2];
  const float* bq  = (const float*)d_in[3];
  const float* Wkv = (const float*)d_in[4];
  const float* bkv = (const float*)d_in[5];
  const float* Wo  = (const float*)d_in[6];
  const float* bo  = (const float*)d_in[7];
  const float* dww = (const float*)d_in[8];
  const float* dwb = (const float*)d_in[9];
  const float* sce = (const float*)d_in[10];
  const float* she = (const float*)d_in[11];
  const float* W1  = (const float*)d_in[12];
  const float* b1  = (const float*)d_in[13];
  const float* W2  = (const float*)d_in[14];
  const float* b2  = (const float*)d_in[15];
  const float* aux = (const float*)d_in[16];
  float* out = (float*)d_out;

  char* ws = (char*)d_ws;
  unsigned short* xt   = (unsigned short*)(ws + 0);              // 64 MB
  unsigned short* P    = (unsigned short*)(ws + (64u  << 20));   // 64 MB
  char*           ylnq = (char*)(ws + (64u << 20));              // 32 MB (overlays P; P dead)
  float*          ysc  = (float*)(ws + (100u << 20));            // 256 KB
  unsigned short* rs   = (unsigned short*)(ws + (128u << 20));   // 64 MB (bf16)
  char*           H1Q  = (char*)(ws + (192u << 20));             // 96 MB (i8)
  char* sm = ws + (384u << 20);
  float*          kv   = (float*)(sm);                           // 256 KB
  float*          cb   = (float*)(sm + 262144);                  // 2 KB
  unsigned short* MT   = (unsigned short*)(sm + 264192);         // 512 KB
  unsigned short* VoT  = (unsigned short*)(sm + 788480);         // 512 KB
  char*           W1Q  = (char*)(sm + 1312768);                  // 768 KB
  char*           W2Q  = (char*)(sm + 2099200);                  // 768 KB
  float*          w1s  = (float*)(sm + 2885632);                 // 6 KB
  float*          w2s  = (float*)(sm + 2891776);                 // 2 KB

  pre_a<<<dim3(288),  dim3(256), 0, stream>>>(aux, Wkv, bkv, W1, W2, kv, w1s, w2s);
  pre_b<<<dim3(1024), dim3(256), 0, stream>>>(Wq, bq, Wo, kv, MT, cb, VoT);
  pre_w<<<dim3(192),  dim3(256), 0, stream>>>(W1, W2, w1s, w2s, W1Q, W2Q);
  xt_kernel<<<dim3(64, 8, 16), dim3(256), 0, stream>>>(x, xt);

  // attention as two m97-structure GEMMs with packed/bounced epilogues
  gemm_mfma<512, 512, 4, 1><<<dim3(2048), dim3(256), 0, stream>>>(
      xt, MT, cb, P, nullptr, nullptr);
  gemm_mfma<512, 512, 4, 4><<<dim3(2048), dim3(256), 0, stream>>>(
      P, VoT, bo, rs, xt, nullptr);
  convq_kernel<<<dim3(256, 16), dim3(256), 0, stream>>>(rs, dww, dwb, ids, sce, she,
                                                        ylnq, ysc);
  // MLP as two int8 8-wave GEMMs with coalesced epilogues
  gemm8w<1536, 512, 6, 3><<<dim3(3072), dim3(512), 0, stream>>>(
      ylnq, W1Q, ysc, w1s, b1, H1Q, nullptr, nullptr);
  gemm8w<512, 1536, 2, 5><<<dim3(1024), dim3(512), 0, stream>>>(
      H1Q, W2Q, nullptr, w2s, b2, nullptr, rs, out);
}

// Round 17
// 665.851 us; speedup vs baseline: 1.0992x; 1.0992x over previous
//
#include <hip/hip_runtime.h>
#include <hip/hip_bf16.h>
#include <math.h>

#define B_ 16
#define C_ 512
#define T_ 4096
#define I_ 1536

typedef short short8 __attribute__((ext_vector_type(8)));
typedef unsigned short ushort8 __attribute__((ext_vector_type(8)));
typedef unsigned short us4 __attribute__((ext_vector_type(4)));
typedef float f32x4 __attribute__((ext_vector_type(4)));
typedef int i32x4 __attribute__((ext_vector_type(4)));
typedef char char8v __attribute__((ext_vector_type(8)));

static __device__ __forceinline__ unsigned short f2bf(float f) {
  union { float f; unsigned int u; } v; v.f = f;
  unsigned int r = v.u + 0x7fffu + ((v.u >> 16) & 1u);
  return (unsigned short)(r >> 16);
}
static __device__ __forceinline__ float bf2f(unsigned short h) {
  union { unsigned int u; float f; } v; v.u = ((unsigned int)h) << 16;
  return v.f;
}

static __device__ __forceinline__ float fast_rcp(float x) {
  float r; asm("v_rcp_f32 %0, %1" : "=v"(r) : "v"(x)); return r;
}

// tanh-form GELU. |err vs erf| <= ~3e-3/elem, diluted by @W2.
static __device__ __forceinline__ float gelu_f(float v) {
  const float v2 = v * v;
  const float w = v * (0.7978845608f + 0.0356774081f * v2);
  const float a = fminf(w * 2.8853900818f, 126.0f);
  const float u = exp2f(a);
  return v * u * fast_rcp(u + 1.0f);
}

static __device__ __forceinline__ int q8i(float v, float inv) {
  int q = __float2int_rn(v * inv);
  q = q > 127 ? 127 : (q < -127 ? -127 : q);
  return q;
}
static __device__ __forceinline__ char q8(float v, float inv) {
  return (char)q8i(v, inv);
}

__device__ __forceinline__ void gload_lds16(const void* g, void* l) {
  __builtin_amdgcn_global_load_lds((const __attribute__((address_space(1))) void*)g,
                                   (__attribute__((address_space(3))) void*)l, 16, 0, 0);
}

#define H1S   (3.0f / 127.0f)
#define IH1S  (127.0f / 3.0f)

// kappa-permutation within each 128-col block: kappa = wcbit*64 + lrow*4 + n
// true col  c = wcbit*64 + n*16 + lrow
static __device__ __forceinline__ int kappa_to_c(int k128) {
  const int wcbit = k128 >> 6, lrow = (k128 & 63) >> 2, n = k128 & 3;
  return wcbit * 64 + n * 16 + lrow;
}

// ---------------- precompute stage A: kv + weight scales ----------------

__global__ __launch_bounds__(256) void pre_a(const float* __restrict__ aux,
                                             const float* __restrict__ Wkv,
                                             const float* __restrict__ bkv,
                                             const float* __restrict__ W1,
                                             const float* __restrict__ W2,
                                             float* __restrict__ kv,
                                             float* __restrict__ w1s,
                                             float* __restrict__ w2s) {
  __shared__ unsigned int red;
  const int bid = blockIdx.x;
  const int tid = threadIdx.x;
  if (bid < 256) {
    const int g = bid * 256 + tid;              // 65536 = 64 * 1024
    const int j = g >> 10, cc = g & 1023;
    float s = bkv[cc];
    for (int i = 0; i < C_; ++i) s += aux[j * C_ + i] * Wkv[i * (2 * C_) + cc];
    kv[g] = s;
    return;
  }
  const bool isW1 = bid < 256 + 1536;
  const int n = isW1 ? (bid - 256) : (bid - 256 - 1536);
  const int ROWS = isW1 ? 512 : 1536;
  const int NC   = isW1 ? 1536 : 512;
  const float* W = isW1 ? W1 : W2;
  if (tid == 0) red = 0;
  __syncthreads();
  float amax = 0.f;
  for (int k = tid; k < ROWS; k += 256)
    amax = fmaxf(amax, fabsf(W[(size_t)k * NC + n]));
#pragma unroll
  for (int off = 1; off < 64; off <<= 1)
    amax = fmaxf(amax, __shfl_xor(amax, off));
  if ((tid & 63) == 0) atomicMax(&red, __float_as_uint(amax));
  __syncthreads();
  if (tid == 0) (isW1 ? w1s : w2s)[n] = fmaxf(__uint_as_float(red), 1e-20f) / 127.0f;
}

// ---------------- precompute stage B: MT, cb, VoT(kappa), W1Q, W2Q(kappa) ----------------

__global__ __launch_bounds__(256) void pre_b(const float* __restrict__ Wq,
                                             const float* __restrict__ bq,
                                             const float* __restrict__ Wo,
                                             const float* __restrict__ kv,
                                             const float* __restrict__ W1,
                                             const float* __restrict__ W2,
                                             const float* __restrict__ w1s,
                                             const float* __restrict__ w2s,
                                             unsigned short* __restrict__ MT,
                                             float* __restrict__ cbias,
                                             unsigned short* __restrict__ VoT,
                                             char* __restrict__ W1Q,
                                             char* __restrict__ W2Q) {
  const int bid = blockIdx.x;
  const int tid = threadIdx.x;
  if (bid < 512) {
    const int col = bid;
    const int h = col >> 6, j = col & 63;
    const float* kvp = kv + j * 1024 + h * 64;
    for (int c = tid; c < C_; c += 256) {
      float s = 0.f;
      for (int d = 0; d < 64; ++d) s += Wq[(size_t)c * C_ + h * 64 + d] * kvp[d];
      MT[(size_t)col * C_ + c] = f2bf(0.125f * s);
    }
    if (tid == 0) {
      float s = 0.f;
      for (int d = 0; d < 64; ++d) s += bq[h * 64 + d] * kvp[d];
      cbias[col] = 0.125f * s;
    }
  } else if (bid < 1024) {
    const int cp = bid - 512;
    for (int k = tid; k < 512; k += 256) {
      const int c = (k >> 7) * 128 + kappa_to_c(k & 127);   // true attention col
      const int h = c >> 6, j = c & 63;
      float s = 0.f;
      for (int d = 0; d < 64; ++d)
        s += kv[j * 1024 + 512 + h * 64 + d] * Wo[(size_t)(h * 64 + d) * C_ + cp];
      VoT[(size_t)cp * 512 + k] = f2bf(s);
    }
  } else if (bid < 4096) {
    const int g = (bid - 1024) * 256 + tid;      // 1536*512
    const int n = g >> 9, k = g & 511;
    W1Q[g] = q8(W1[(size_t)k * I_ + n], 1.0f / w1s[n]);
  } else {
    const int g = (bid - 4096) * 256 + tid;      // 512*1536 : W2Q[n][k] kappa-order
    const int n = g / 1536, k = g - n * 1536;
    const int c = (k >> 7) * 128 + kappa_to_c(k & 127);     // true I-channel
    W2Q[g] = q8(W2[(size_t)c * C_ + n], 1.0f / w2s[n]);
  }
}

// ---------------- x (B,C,T) -> xt bf16 (B*T, C), vectorized stores ----------------

__global__ __launch_bounds__(256) void xt_kernel(const float* __restrict__ x,
                                                 unsigned short* __restrict__ xt) {
  __shared__ float ld[64][65];
  const int tid = threadIdx.x;
  const int t0 = blockIdx.x * 64, c0 = blockIdx.y * 64, b = blockIdx.z;
  for (int idx = tid; idx < 4096; idx += 256) {
    const int r = idx >> 6, cc = idx & 63;
    ld[r][cc] = x[((size_t)(b * C_ + c0 + r)) * T_ + t0 + cc];
  }
  __syncthreads();
#pragma unroll
  for (int s = 0; s < 2; ++s) {
    const int idx = s * 256 + tid;      // 512 = 64 t-rows x 8 col-chunks
    const int tr = idx >> 3, cl8 = (idx & 7) * 8;
    ushort8 o;
#pragma unroll
    for (int qv = 0; qv < 8; ++qv) o[qv] = f2bf(ld[cl8 + qv][tr]);
    *(ushort8*)&xt[((size_t)(b * T_ + t0 + tr)) * C_ + c0 + cl8] = o;
  }
}

// ---------------- GEMM A (m97 structure): attention GEMMs ----------------
// EPI 1: softmax epilogue, P stored kappa-packed (ushort4 per (m,i)).
// EPI 4: LDS-bounce [c][t] bf16 tile -> coalesced full-row ushort8 stores of rs.
template<int N, int K, int NCOL, int EPI>
__global__ __launch_bounds__(256) void gemm_mfma(const unsigned short* __restrict__ A,
                                                 const unsigned short* __restrict__ Bt,
                                                 const float* __restrict__ bias,
                                                 unsigned short* __restrict__ outU,
                                                 const unsigned short* __restrict__ resU,
                                                 float* __restrict__ outF) {
  __shared__ __align__(16) unsigned short lA[128 * 32];
  __shared__ __align__(16) unsigned short lB[128 * 32];
  __shared__ __align__(16) unsigned short bounce[EPI == 4 ? 128 * 132 : 8];
  const int q = gridDim.x >> 3;
  const int wgid = (blockIdx.x & 7) * q + (blockIdx.x >> 3);
  const int row0 = (wgid / NCOL) * 128;
  const int col0 = (wgid % NCOL) * 128;
  const int tid = threadIdx.x;
  const int w = tid >> 6, lane = tid & 63;
  const int wr = (w >> 1) * 64, wc = (w & 1) * 64;
  const int c1 = tid, c2 = tid + 256;

  const f32x4 zero4 = {0.f, 0.f, 0.f, 0.f};
  f32x4 acc[4][4];
#pragma unroll
  for (int m = 0; m < 4; ++m)
#pragma unroll
    for (int n = 0; n < 4; ++n) acc[m][n] = zero4;

  const size_t aBase = (size_t)row0 * K;
  const size_t bBase = (size_t)col0 * K;
  const int lrow = lane & 15, lg = lane >> 4;

  for (int k0 = 0; k0 < K; k0 += 32) {
    gload_lds16(A + aBase + (size_t)(c1 & 127) * K + k0 + (c1 >> 7) * 8, (char*)lA + c1 * 16);
    gload_lds16(A + aBase + (size_t)(c2 & 127) * K + k0 + (c2 >> 7) * 8, (char*)lA + c2 * 16);
    gload_lds16(Bt + bBase + (size_t)(c1 & 127) * K + k0 + (c1 >> 7) * 8, (char*)lB + c1 * 16);
    gload_lds16(Bt + bBase + (size_t)(c2 & 127) * K + k0 + (c2 >> 7) * 8, (char*)lB + c2 * 16);
    __syncthreads();
    short8 av[4], bv[4];
#pragma unroll
    for (int m = 0; m < 4; ++m)
      av[m] = *(const short8*)&lA[(lg * 128 + wr + m * 16 + lrow) * 8];
#pragma unroll
    for (int n = 0; n < 4; ++n)
      bv[n] = *(const short8*)&lB[(lg * 128 + wc + n * 16 + lrow) * 8];
#pragma unroll
    for (int m = 0; m < 4; ++m)
#pragma unroll
      for (int n = 0; n < 4; ++n)
        acc[m][n] = __builtin_amdgcn_mfma_f32_16x16x32_bf16(av[m], bv[n], acc[m][n], 0, 0, 0);
    __syncthreads();
  }

  if (EPI == 1) {
    float cbv[4];
#pragma unroll
    for (int n = 0; n < 4; ++n) cbv[n] = bias[col0 + wc + n * 16 + lrow];
    const int kbase = col0 + wc + lrow * 4;     // kappa address of this thread's 4 cols
#pragma unroll
    for (int m = 0; m < 4; ++m) {
#pragma unroll
      for (int i = 0; i < 4; ++i) {
        float e0 = acc[m][0][i] + cbv[0];
        float e1 = acc[m][1][i] + cbv[1];
        float e2 = acc[m][2][i] + cbv[2];
        float e3 = acc[m][3][i] + cbv[3];
        float mx = fmaxf(fmaxf(e0, e1), fmaxf(e2, e3));
        mx = fmaxf(mx, __shfl_xor(mx, 1));
        mx = fmaxf(mx, __shfl_xor(mx, 2));
        mx = fmaxf(mx, __shfl_xor(mx, 4));
        mx = fmaxf(mx, __shfl_xor(mx, 8));
        e0 = __expf(e0 - mx); e1 = __expf(e1 - mx);
        e2 = __expf(e2 - mx); e3 = __expf(e3 - mx);
        float s = e0 + e1 + e2 + e3;
        s += __shfl_xor(s, 1);
        s += __shfl_xor(s, 2);
        s += __shfl_xor(s, 4);
        s += __shfl_xor(s, 8);
        const float inv = 1.0f / s;
        us4 pk;
        pk[0] = f2bf(e0 * inv); pk[1] = f2bf(e1 * inv);
        pk[2] = f2bf(e2 * inv); pk[3] = f2bf(e3 * inv);
        *(us4*)&outU[(size_t)(row0 + wr + m * 16 + lg * 4 + i) * N + kbase] = pk;
      }
    }
    return;
  }

  // EPI == 4 : residual epilogue with LDS transpose bounce
#pragma unroll
  for (int m = 0; m < 4; ++m) {
    const int r0 = row0 + wr + m * 16 + (lg << 2);
    const int tl = wr + m * 16 + (lg << 2);
#pragma unroll
    for (int n = 0; n < 4; ++n) {
      const int cl = wc + n * 16 + lrow;
      const int c = col0 + cl;
      const float bb = bias[c];
      us4 pk;
#pragma unroll
      for (int i = 0; i < 4; ++i)
        pk[i] = f2bf(bf2f(resU[(size_t)(r0 + i) * 512 + c]) + acc[m][n][i] + bb);
      *(us4*)&bounce[cl * 132 + tl] = pk;
    }
  }
  __syncthreads();
  const int bidx = row0 >> 12;
  const int t0 = row0 & 4095;
#pragma unroll
  for (int j = 0; j < 8; ++j) {
    const int cl = j * 16 + w * 4 + (lane >> 4);
    const int t = (lane & 15) * 8;
    const ushort8 v = *(const ushort8*)&bounce[cl * 132 + t];
    *(ushort8*)&outU[((size_t)(bidx * C_ + col0 + cl)) * T_ + t0 + t] = v;
  }
}

// ---------------- GEMM B: int8, 8 waves, 128x256 tile, BK=64, 3-buf ----------------
// EPI 3: kappa-packed char4 stores of H1Q. EPI 5: 2-pass LDS-bounce coalesced f32 stores.
template<int N, int K, int NCOL, int EPI>
__global__ __launch_bounds__(512, 4) void gemm8w(const char* __restrict__ A,
                                                 const char* __restrict__ Bt,
                                                 const float* __restrict__ rowS,
                                                 const float* __restrict__ colS,
                                                 const float* __restrict__ bias,
                                                 char* __restrict__ outQ,
                                                 const unsigned short* __restrict__ resU,
                                                 float* __restrict__ outF) {
  __shared__ __align__(16) char lds[73728];
  const int tid = threadIdx.x;
  const int w = tid >> 6, lane = tid & 63;
  const int wm = w >> 2, wn = w & 3;            // 2x4 wave grid
  const int lrow = lane & 15, lg = lane >> 4;
  const int q8g = gridDim.x >> 3;
  const int wgid = (blockIdx.x & 7) * q8g + (blockIdx.x >> 3);
  const int row0 = (wgid / NCOL) * 128;
  const int col0 = (wgid % NCOL) * 128 * 2;     // BN=256

  auto stageA = [&](int kt, int b) {
    gload_lds16(A + (size_t)(row0 + (tid & 127)) * K + kt * 64 + (tid >> 7) * 16,
                lds + b * 8192 + tid * 16);
  };
  auto stageB = [&](int kt, int b) {
#pragma unroll
    for (int s = 0; s < 2; ++s) {
      const int q = s * 512 + tid;
      gload_lds16(Bt + (size_t)(col0 + (q & 255)) * K + kt * 64 + (q >> 8) * 16,
                  lds + 24576 + b * 16384 + q * 16);
    }
  };

  const i32x4 zero4 = {0, 0, 0, 0};
  i32x4 acc[4][4];
#pragma unroll
  for (int m = 0; m < 4; ++m)
#pragma unroll
    for (int n = 0; n < 4; ++n) acc[m][n] = zero4;

  const int KT = K / 64;     // G3: 8, G4: 24

  stageA(0, 0); stageB(0, 0);
  stageA(1, 1); stageB(1, 1);
  asm volatile("s_waitcnt vmcnt(3)" ::: "memory");
  __builtin_amdgcn_s_barrier();

  int cur = 0;
  for (int t = 0; t < KT; ++t) {
    if (t + 2 < KT) {
      const int nb = (cur + 2 >= 3) ? cur - 1 : cur + 2;
      stageA(t + 2, nb); stageB(t + 2, nb);
    }
    const char* ab = lds + cur * 8192;
    const char* bb = lds + 24576 + cur * 16384;
    i32x4 av[4], bv[4];
#pragma unroll
    for (int mf = 0; mf < 4; ++mf)
      av[mf] = *(const i32x4*)(ab + (size_t)(lg * 128 + wm * 64 + mf * 16 + lrow) * 16);
#pragma unroll
    for (int nf = 0; nf < 4; ++nf)
      bv[nf] = *(const i32x4*)(bb + (size_t)(lg * 256 + wn * 64 + nf * 16 + lrow) * 16);
    __builtin_amdgcn_s_setprio(1);
#pragma unroll
    for (int mf = 0; mf < 4; ++mf)
#pragma unroll
      for (int nf = 0; nf < 4; ++nf)
        acc[mf][nf] = __builtin_amdgcn_mfma_i32_16x16x64_i8(av[mf], bv[nf],
                                                            acc[mf][nf], 0, 0, 0);
    __builtin_amdgcn_s_setprio(0);
    if (t + 2 < KT) { asm volatile("s_waitcnt vmcnt(3)" ::: "memory"); }
    else            { asm volatile("s_waitcnt vmcnt(0)" ::: "memory"); }
    __builtin_amdgcn_s_barrier();
    cur = (cur == 2) ? 0 : cur + 1;
  }

  if (EPI == 3) {
    const int kbase = col0 + (wn >> 1) * 128 + (wn & 1) * 64 + lrow * 4;
#pragma unroll
    for (int mf = 0; mf < 4; ++mf) {
      const int r0 = row0 + wm * 64 + mf * 16 + lg * 4;
      float rs4[4];
#pragma unroll
      for (int i = 0; i < 4; ++i) rs4[i] = rowS[r0 + i];
      float dsv[4], bbv[4];
#pragma unroll
      for (int nf = 0; nf < 4; ++nf) {
        const int c = col0 + wn * 64 + nf * 16 + lrow;
        dsv[nf] = colS[c];
        bbv[nf] = bias[c];
      }
#pragma unroll
      for (int i = 0; i < 4; ++i) {
        unsigned int pk = 0;
#pragma unroll
        for (int nf = 0; nf < 4; ++nf) {
          const float v = fmaf((float)acc[mf][nf][i], rs4[i] * dsv[nf], bbv[nf]);
          const float g = gelu_f(v);
          const unsigned int b =
              (unsigned int)(unsigned char)(char)q8i(fminf(fmaxf(g, -3.0f), 3.0f), IH1S);
          pk |= b << (8 * nf);
        }
        *(unsigned int*)&outQ[(size_t)(r0 + i) * N + kbase] = pk;
      }
    }
    return;
  }

  // EPI == 5 : 2-pass LDS bounce (128c x 128t f32, stride 132) -> coalesced stores
  float* fb = (float*)lds;
  const int bidx = row0 >> 12;
  const int t0 = row0 & 4095;
#pragma unroll
  for (int p = 0; p < 2; ++p) {
    if ((wn >> 1) == p) {
#pragma unroll
      for (int mf = 0; mf < 4; ++mf) {
        const int tl = wm * 64 + mf * 16 + lg * 4;
#pragma unroll
        for (int nf = 0; nf < 4; ++nf) {
          const int cl = (wn & 1) * 64 + nf * 16 + lrow;
          const int c = col0 + p * 128 + cl;
          const float ds = H1S * colS[c];
          const float bb = bias[c];
          f32x4 v;
#pragma unroll
          for (int i = 0; i < 4; ++i) v[i] = fmaf((float)acc[mf][nf][i], ds, bb);
          *(f32x4*)&fb[cl * 132 + tl] = v;
        }
      }
    }
    __syncthreads();
#pragma unroll
    for (int j = 0; j < 8; ++j) {
      const int cl = j * 16 + w * 2 + (lane >> 5);
      const int t = (lane & 31) * 4;
      const f32x4 v = *(const f32x4*)&fb[cl * 132 + t];
      const size_t addr = ((size_t)(bidx * C_ + col0 + p * 128 + cl)) * T_ + t0 + t;
      const us4 rv = *(const us4*)&resU[addr];
      f32x4 o;
#pragma unroll
      for (int i = 0; i < 4; ++i) o[i] = v[i] + bf2f(rv[i]);
      *(f32x4*)&outF[addr] = o;
    }
    __syncthreads();
  }
}

// ---------------- fused conv1d(k=7,p=3) + AdaLayerNorm -> int8 yln + per-token scale ----------------

__global__ __launch_bounds__(256) void convq_kernel(
    const unsigned short* __restrict__ rs,
    const float* __restrict__ dww,
    const float* __restrict__ dwb,
    const int* __restrict__ ids,
    const float* __restrict__ sce,
    const float* __restrict__ she,
    char* __restrict__ ylnq,
    float* __restrict__ yscale) {
  __shared__ float cbuf[16 * 520];
  const int tid = threadIdx.x;
  const int t0 = blockIdx.x * 16;
  const int b = blockIdx.y;
#pragma unroll
  for (int cc = 0; cc < 2; ++cc) {
    const int c = cc * 256 + tid;
    float f[24];
#pragma unroll
    for (int j = 0; j < 6; ++j) {
      const int t = t0 - 4 + j * 4;
      if (t >= 0 && t < T_) {
        const us4 v = *(const us4*)&rs[((size_t)(b * C_ + c)) * T_ + t];
#pragma unroll
        for (int i = 0; i < 4; ++i) f[j * 4 + i] = bf2f(v[i]);
      } else {
#pragma unroll
        for (int i = 0; i < 4; ++i) f[j * 4 + i] = 0.f;
      }
    }
    float wk[7];
#pragma unroll
    for (int k = 0; k < 7; ++k) wk[k] = dww[c * 7 + k];
    const float bb = dwb[c];
#pragma unroll
    for (int tt = 0; tt < 16; ++tt) {
      float s = bb;
#pragma unroll
      for (int k = 0; k < 7; ++k) s += f[tt + 1 + k] * wk[k];
      cbuf[tt * 520 + c] = s;
    }
  }
  __syncthreads();
  const int lane = tid & 63, w = tid >> 6;
  const int id = ids[b];
#pragma unroll
  for (int tt = 0; tt < 4; ++tt) {
    const int t = w * 4 + tt;
    const f32x4 v0 = *(const f32x4*)&cbuf[t * 520 + lane * 8];
    const f32x4 v1 = *(const f32x4*)&cbuf[t * 520 + lane * 8 + 4];
    float s = 0.f, sq = 0.f;
#pragma unroll
    for (int i = 0; i < 4; ++i) { s += v0[i]; sq += v0[i] * v0[i]; }
#pragma unroll
    for (int i = 0; i < 4; ++i) { s += v1[i]; sq += v1[i] * v1[i]; }
#pragma unroll
    for (int off = 1; off < 64; off <<= 1) {
      s += __shfl_xor(s, off);
      sq += __shfl_xor(sq, off);
    }
    const float mean = s * (1.0f / 512.0f);
    const float var = sq * (1.0f / 512.0f) - mean * mean;
    const float rstd = rsqrtf(var + 1e-6f);
    const f32x4 sc0 = *(const f32x4*)&sce[id * C_ + lane * 8];
    const f32x4 sc1 = *(const f32x4*)&sce[id * C_ + lane * 8 + 4];
    const f32x4 sh0 = *(const f32x4*)&she[id * C_ + lane * 8];
    const f32x4 sh1 = *(const f32x4*)&she[id * C_ + lane * 8 + 4];
    float y[8];
    float amax = 0.f;
#pragma unroll
    for (int i = 0; i < 4; ++i) {
      y[i]     = (v0[i] - mean) * rstd * sc0[i] + sh0[i];
      y[4 + i] = (v1[i] - mean) * rstd * sc1[i] + sh1[i];
    }
#pragma unroll
    for (int i = 0; i < 8; ++i) amax = fmaxf(amax, fabsf(y[i]));
#pragma unroll
    for (int off = 1; off < 64; off <<= 1) amax = fmaxf(amax, __shfl_xor(amax, off));
    amax = fmaxf(amax, 1e-20f);
    const float inv = 127.0f / amax;
    const int tg = b * T_ + t0 + t;
    char8v o;
#pragma unroll
    for (int i = 0; i < 8; ++i) o[i] = q8(y[i], inv);
    *(char8v*)&ylnq[(size_t)tg * C_ + lane * 8] = o;
    if (lane == 0) yscale[tg] = amax * (1.0f / 127.0f);
  }
}

// ---------------- launch ----------------

extern "C" void kernel_launch(void* const* d_in, const int* in_sizes, int n_in,
                              void* d_out, int out_size, void* d_ws, size_t ws_size,
                              hipStream_t stream) {
  const float* x   = (const float*)d_in[0];
  const int*   ids = (const int*)d_in[1];
  const float* Wq  = (const float*)d_in[2];
  const float* bq  = (const float*)d_in[3];
  const float* Wkv = (const float*)d_in[4];
  const float* bkv = (const float*)d_in[5];
  const float* Wo  = (const float*)d_in[6];
  const float* bo  = (const float*)d_in[7];
  const float* dww = (const float*)d_in[8];
  const float* dwb = (const float*)d_in[9];
  const float* sce = (const float*)d_in[10];
  const float* she = (const float*)d_in[11];
  const float* W1  = (const float*)d_in[12];
  const float* b1  = (const float*)d_in[13];
  const float* W2  = (const float*)d_in[14];
  const float* b2  = (const float*)d_in[15];
  const float* aux = (const float*)d_in[16];
  float* out = (float*)d_out;

  char* ws = (char*)d_ws;
  unsigned short* xt   = (unsigned short*)(ws + 0);              // 64 MB
  unsigned short* P    = (unsigned short*)(ws + (64u  << 20));   // 64 MB
  char*           ylnq = (char*)(ws + (64u << 20));              // 32 MB (overlays P; P dead)
  float*          ysc  = (float*)(ws + (100u << 20));            // 256 KB
  unsigned short* rs   = (unsigned short*)(ws + (128u << 20));   // 64 MB (bf16)
  char*           H1Q  = (char*)(ws + (192u << 20));             // 96 MB (i8)
  char* sm = ws + (384u << 20);
  float*          kv   = (float*)(sm);                           // 256 KB
  float*          cb   = (float*)(sm + 262144);                  // 2 KB
  unsigned short* MT   = (unsigned short*)(sm + 264192);         // 512 KB
  unsigned short* VoT  = (unsigned short*)(sm + 788480);         // 512 KB
  char*           W1Q  = (char*)(sm + 1312768);                  // 768 KB
  char*           W2Q  = (char*)(sm + 2099200);                  // 768 KB
  float*          w1s  = (float*)(sm + 2885632);                 // 6 KB
  float*          w2s  = (float*)(sm + 2891776);                 // 2 KB

  pre_a<<<dim3(2304), dim3(256), 0, stream>>>(aux, Wkv, bkv, W1, W2, kv, w1s, w2s);
  pre_b<<<dim3(7168), dim3(256), 0, stream>>>(Wq, bq, Wo, kv, W1, W2, w1s, w2s,
                                              MT, cb, VoT, W1Q, W2Q);
  xt_kernel<<<dim3(64, 8, 16), dim3(256), 0, stream>>>(x, xt);

  // attention as two m97-structure GEMMs with packed/bounced epilogues
  gemm_mfma<512, 512, 4, 1><<<dim3(2048), dim3(256), 0, stream>>>(
      xt, MT, cb, P, nullptr, nullptr);
  gemm_mfma<512, 512, 4, 4><<<dim3(2048), dim3(256), 0, stream>>>(
      P, VoT, bo, rs, xt, nullptr);
  convq_kernel<<<dim3(256, 16), dim3(256), 0, stream>>>(rs, dww, dwb, ids, sce, she,
                                                        ylnq, ysc);
  // MLP as two int8 8-wave GEMMs with coalesced epilogues
  gemm8w<1536, 512, 6, 3><<<dim3(3072), dim3(512), 0, stream>>>(
      ylnq, W1Q, ysc, w1s, b1, H1Q, nullptr, nullptr);
  gemm8w<512, 1536, 2, 5><<<dim3(1024), dim3(512), 0, stream>>>(
      H1Q, W2Q, nullptr, w2s, b2, nullptr, rs, out);
}

// Round 18
// 545.698 us; speedup vs baseline: 1.3413x; 1.2202x over previous
//
#include <hip/hip_runtime.h>
#include <hip/hip_bf16.h>
#include <math.h>

#define B_ 16
#define C_ 512
#define T_ 4096
#define I_ 1536

typedef short short8 __attribute__((ext_vector_type(8)));
typedef unsigned short ushort8 __attribute__((ext_vector_type(8)));
typedef unsigned short us4 __attribute__((ext_vector_type(4)));
typedef float f32x4 __attribute__((ext_vector_type(4)));
typedef int i32x4 __attribute__((ext_vector_type(4)));
typedef char char8v __attribute__((ext_vector_type(8)));

static __device__ __forceinline__ unsigned short f2bf(float f) {
  union { float f; unsigned int u; } v; v.f = f;
  unsigned int r = v.u + 0x7fffu + ((v.u >> 16) & 1u);
  return (unsigned short)(r >> 16);
}
static __device__ __forceinline__ float bf2f(unsigned short h) {
  union { unsigned int u; float f; } v; v.u = ((unsigned int)h) << 16;
  return v.f;
}

static __device__ __forceinline__ float fast_rcp(float x) {
  float r; asm("v_rcp_f32 %0, %1" : "=v"(r) : "v"(x)); return r;
}

// tanh-form GELU. |err vs erf| <= ~3e-3/elem, diluted by @W2.
static __device__ __forceinline__ float gelu_f(float v) {
  const float v2 = v * v;
  const float w = v * (0.7978845608f + 0.0356774081f * v2);
  const float a = fminf(w * 2.8853900818f, 126.0f);
  const float u = exp2f(a);
  return v * u * fast_rcp(u + 1.0f);
}

static __device__ __forceinline__ int q8i(float v, float inv) {
  int q = __float2int_rn(v * inv);
  q = q > 127 ? 127 : (q < -127 ? -127 : q);
  return q;
}
static __device__ __forceinline__ char q8(float v, float inv) {
  return (char)q8i(v, inv);
}

__device__ __forceinline__ void gload_lds16(const void* g, void* l) {
  __builtin_amdgcn_global_load_lds((const __attribute__((address_space(1))) void*)g,
                                   (__attribute__((address_space(3))) void*)l, 16, 0, 0);
}

#define H1S   (3.0f / 127.0f)
#define IH1S  (127.0f / 3.0f)

// kappa-permutation within each 128-col block: kappa = wcbit*64 + lrow*4 + n
// true col  c = wcbit*64 + n*16 + lrow
static __device__ __forceinline__ int kappa_to_c(int k128) {
  const int wcbit = k128 >> 6, lrow = (k128 & 63) >> 2, n = k128 & 3;
  return wcbit * 64 + n * 16 + lrow;
}

// staging chunk swizzle: lane q stages (row=q>>2, kc=(q&3)^((row>>1)&3)); the
// four 16B chunks of each 64B row-segment are read by 4 consecutive lanes ->
// fully coalesced (16 full lines/wave vs 64 partial). Fragment ds_read index
// (row*4 + (lg^((row>>1)&3))) spreads 16-lane groups over 8 slots -> 2-way (free).
static __device__ __forceinline__ int swz_kc(int q, int row) {
  return (q & 3) ^ ((row >> 1) & 3);
}
static __device__ __forceinline__ int swz_rd(int row, int lg) {
  return row * 4 + (lg ^ ((row >> 1) & 3));
}

// ---------------- precompute stage A: kv + weight scales ----------------

__global__ __launch_bounds__(256) void pre_a(const float* __restrict__ aux,
                                             const float* __restrict__ Wkv,
                                             const float* __restrict__ bkv,
                                             const float* __restrict__ W1,
                                             const float* __restrict__ W2,
                                             float* __restrict__ kv,
                                             float* __restrict__ w1s,
                                             float* __restrict__ w2s) {
  __shared__ unsigned int red;
  const int bid = blockIdx.x;
  const int tid = threadIdx.x;
  if (bid < 256) {
    const int g = bid * 256 + tid;              // 65536 = 64 * 1024
    const int j = g >> 10, cc = g & 1023;
    float s = bkv[cc];
    for (int i = 0; i < C_; ++i) s += aux[j * C_ + i] * Wkv[i * (2 * C_) + cc];
    kv[g] = s;
    return;
  }
  const bool isW1 = bid < 256 + 1536;
  const int n = isW1 ? (bid - 256) : (bid - 256 - 1536);
  const int ROWS = isW1 ? 512 : 1536;
  const int NC   = isW1 ? 1536 : 512;
  const float* W = isW1 ? W1 : W2;
  if (tid == 0) red = 0;
  __syncthreads();
  float amax = 0.f;
  for (int k = tid; k < ROWS; k += 256)
    amax = fmaxf(amax, fabsf(W[(size_t)k * NC + n]));
#pragma unroll
  for (int off = 1; off < 64; off <<= 1)
    amax = fmaxf(amax, __shfl_xor(amax, off));
  if ((tid & 63) == 0) atomicMax(&red, __float_as_uint(amax));
  __syncthreads();
  if (tid == 0) (isW1 ? w1s : w2s)[n] = fmaxf(__uint_as_float(red), 1e-20f) / 127.0f;
}

// ---------------- precompute stage B: MT, cb, VoT(kappa), W1Q, W2Q(kappa) ----------------

__global__ __launch_bounds__(256) void pre_b(const float* __restrict__ Wq,
                                             const float* __restrict__ bq,
                                             const float* __restrict__ Wo,
                                             const float* __restrict__ kv,
                                             const float* __restrict__ W1,
                                             const float* __restrict__ W2,
                                             const float* __restrict__ w1s,
                                             const float* __restrict__ w2s,
                                             unsigned short* __restrict__ MT,
                                             float* __restrict__ cbias,
                                             unsigned short* __restrict__ VoT,
                                             char* __restrict__ W1Q,
                                             char* __restrict__ W2Q) {
  const int bid = blockIdx.x;
  const int tid = threadIdx.x;
  if (bid < 512) {
    const int col = bid;
    const int h = col >> 6, j = col & 63;
    const float* kvp = kv + j * 1024 + h * 64;
    for (int c = tid; c < C_; c += 256) {
      float s = 0.f;
      for (int d = 0; d < 64; ++d) s += Wq[(size_t)c * C_ + h * 64 + d] * kvp[d];
      MT[(size_t)col * C_ + c] = f2bf(0.125f * s);
    }
    if (tid == 0) {
      float s = 0.f;
      for (int d = 0; d < 64; ++d) s += bq[h * 64 + d] * kvp[d];
      cbias[col] = 0.125f * s;
    }
  } else if (bid < 1024) {
    const int cp = bid - 512;
    for (int k = tid; k < 512; k += 256) {
      const int c = (k >> 7) * 128 + kappa_to_c(k & 127);   // true attention col
      const int h = c >> 6, j = c & 63;
      float s = 0.f;
      for (int d = 0; d < 64; ++d)
        s += kv[j * 1024 + 512 + h * 64 + d] * Wo[(size_t)(h * 64 + d) * C_ + cp];
      VoT[(size_t)cp * 512 + k] = f2bf(s);
    }
  } else if (bid < 4096) {
    const int g = (bid - 1024) * 256 + tid;      // 1536*512
    const int n = g >> 9, k = g & 511;
    W1Q[g] = q8(W1[(size_t)k * I_ + n], 1.0f / w1s[n]);
  } else {
    const int g = (bid - 4096) * 256 + tid;      // 512*1536 : W2Q[n][k] kappa-order
    const int n = g / 1536, k = g - n * 1536;
    const int c = (k >> 7) * 128 + kappa_to_c(k & 127);     // true I-channel
    W2Q[g] = q8(W2[(size_t)c * C_ + n], 1.0f / w2s[n]);
  }
}

// ---------------- x (B,C,T) -> xt bf16 (B*T, C), vectorized stores ----------------

__global__ __launch_bounds__(256) void xt_kernel(const float* __restrict__ x,
                                                 unsigned short* __restrict__ xt) {
  __shared__ float ld[64][65];
  const int tid = threadIdx.x;
  const int t0 = blockIdx.x * 64, c0 = blockIdx.y * 64, b = blockIdx.z;
  for (int idx = tid; idx < 4096; idx += 256) {
    const int r = idx >> 6, cc = idx & 63;
    ld[r][cc] = x[((size_t)(b * C_ + c0 + r)) * T_ + t0 + cc];
  }
  __syncthreads();
#pragma unroll
  for (int s = 0; s < 2; ++s) {
    const int idx = s * 256 + tid;      // 512 = 64 t-rows x 8 col-chunks
    const int tr = idx >> 3, cl8 = (idx & 7) * 8;
    ushort8 o;
#pragma unroll
    for (int qv = 0; qv < 8; ++qv) o[qv] = f2bf(ld[cl8 + qv][tr]);
    *(ushort8*)&xt[((size_t)(b * T_ + t0 + tr)) * C_ + c0 + cl8] = o;
  }
}

// ---------------- GEMM A (m97 structure, coalesced swizzled staging): attention GEMMs ------
// EPI 1: softmax epilogue, P stored kappa-packed (ushort4 per (m,i)).
// EPI 4: LDS-bounce [c][t] bf16 tile -> coalesced full-row ushort8 stores of rs.
template<int N, int K, int NCOL, int EPI>
__global__ __launch_bounds__(256) void gemm_mfma(const unsigned short* __restrict__ A,
                                                 const unsigned short* __restrict__ Bt,
                                                 const float* __restrict__ bias,
                                                 unsigned short* __restrict__ outU,
                                                 const unsigned short* __restrict__ resU,
                                                 float* __restrict__ outF) {
  __shared__ __align__(16) unsigned short lA[128 * 32];
  __shared__ __align__(16) unsigned short lB[128 * 32];
  __shared__ __align__(16) unsigned short bounce[EPI == 4 ? 128 * 132 : 8];
  const int q = gridDim.x >> 3;
  const int wgid = (blockIdx.x & 7) * q + (blockIdx.x >> 3);
  const int row0 = (wgid / NCOL) * 128;
  const int col0 = (wgid % NCOL) * 128;
  const int tid = threadIdx.x;
  const int w = tid >> 6, lane = tid & 63;
  const int wr = (w >> 1) * 64, wc = (w & 1) * 64;
  const int c1 = tid, c2 = tid + 256;
  // coalesced staging coords (chunk = 16B = 8 bf16)
  const int r1 = c1 >> 2, kc1 = swz_kc(c1, r1);
  const int r2 = c2 >> 2, kc2 = swz_kc(c2, r2);

  const f32x4 zero4 = {0.f, 0.f, 0.f, 0.f};
  f32x4 acc[4][4];
#pragma unroll
  for (int m = 0; m < 4; ++m)
#pragma unroll
    for (int n = 0; n < 4; ++n) acc[m][n] = zero4;

  const size_t aBase = (size_t)row0 * K;
  const size_t bBase = (size_t)col0 * K;
  const int lrow = lane & 15, lg = lane >> 4;

  for (int k0 = 0; k0 < K; k0 += 32) {
    gload_lds16(A + aBase + (size_t)r1 * K + k0 + kc1 * 8, (char*)lA + c1 * 16);
    gload_lds16(A + aBase + (size_t)r2 * K + k0 + kc2 * 8, (char*)lA + c2 * 16);
    gload_lds16(Bt + bBase + (size_t)r1 * K + k0 + kc1 * 8, (char*)lB + c1 * 16);
    gload_lds16(Bt + bBase + (size_t)r2 * K + k0 + kc2 * 8, (char*)lB + c2 * 16);
    __syncthreads();
    short8 av[4], bv[4];
#pragma unroll
    for (int m = 0; m < 4; ++m) {
      const int ar = wr + m * 16 + lrow;
      av[m] = *(const short8*)&lA[swz_rd(ar, lg) * 8];
    }
#pragma unroll
    for (int n = 0; n < 4; ++n) {
      const int br = wc + n * 16 + lrow;
      bv[n] = *(const short8*)&lB[swz_rd(br, lg) * 8];
    }
#pragma unroll
    for (int m = 0; m < 4; ++m)
#pragma unroll
      for (int n = 0; n < 4; ++n)
        acc[m][n] = __builtin_amdgcn_mfma_f32_16x16x32_bf16(av[m], bv[n], acc[m][n], 0, 0, 0);
    __syncthreads();
  }

  if (EPI == 1) {
    float cbv[4];
#pragma unroll
    for (int n = 0; n < 4; ++n) cbv[n] = bias[col0 + wc + n * 16 + lrow];
    const int kbase = col0 + wc + lrow * 4;     // kappa address of this thread's 4 cols
#pragma unroll
    for (int m = 0; m < 4; ++m) {
#pragma unroll
      for (int i = 0; i < 4; ++i) {
        float e0 = acc[m][0][i] + cbv[0];
        float e1 = acc[m][1][i] + cbv[1];
        float e2 = acc[m][2][i] + cbv[2];
        float e3 = acc[m][3][i] + cbv[3];
        float mx = fmaxf(fmaxf(e0, e1), fmaxf(e2, e3));
        mx = fmaxf(mx, __shfl_xor(mx, 1));
        mx = fmaxf(mx, __shfl_xor(mx, 2));
        mx = fmaxf(mx, __shfl_xor(mx, 4));
        mx = fmaxf(mx, __shfl_xor(mx, 8));
        e0 = __expf(e0 - mx); e1 = __expf(e1 - mx);
        e2 = __expf(e2 - mx); e3 = __expf(e3 - mx);
        float s = e0 + e1 + e2 + e3;
        s += __shfl_xor(s, 1);
        s += __shfl_xor(s, 2);
        s += __shfl_xor(s, 4);
        s += __shfl_xor(s, 8);
        const float inv = 1.0f / s;
        us4 pk;
        pk[0] = f2bf(e0 * inv); pk[1] = f2bf(e1 * inv);
        pk[2] = f2bf(e2 * inv); pk[3] = f2bf(e3 * inv);
        *(us4*)&outU[(size_t)(row0 + wr + m * 16 + lg * 4 + i) * N + kbase] = pk;
      }
    }
    return;
  }

  // EPI == 4 : residual epilogue with LDS transpose bounce
#pragma unroll
  for (int m = 0; m < 4; ++m) {
    const int r0 = row0 + wr + m * 16 + (lg << 2);
    const int tl = wr + m * 16 + (lg << 2);
#pragma unroll
    for (int n = 0; n < 4; ++n) {
      const int cl = wc + n * 16 + lrow;
      const int c = col0 + cl;
      const float bb = bias[c];
      us4 pk;
#pragma unroll
      for (int i = 0; i < 4; ++i)
        pk[i] = f2bf(bf2f(resU[(size_t)(r0 + i) * 512 + c]) + acc[m][n][i] + bb);
      *(us4*)&bounce[cl * 132 + tl] = pk;
    }
  }
  __syncthreads();
  const int bidx = row0 >> 12;
  const int t0 = row0 & 4095;
#pragma unroll
  for (int j = 0; j < 8; ++j) {
    const int cl = j * 16 + w * 4 + (lane >> 4);
    const int t = (lane & 15) * 8;
    const ushort8 v = *(const ushort8*)&bounce[cl * 132 + t];
    *(ushort8*)&outU[((size_t)(bidx * C_ + col0 + cl)) * T_ + t0 + t] = v;
  }
}

// ---------------- GEMM B: int8, 8 waves, 128x256 tile, BK=64, 3-buf, coalesced staging ------
// EPI 3: kappa-packed char4 stores of H1Q. EPI 5: 2-pass LDS-bounce coalesced f32 stores.
template<int N, int K, int NCOL, int EPI>
__global__ __launch_bounds__(512, 4) void gemm8w(const char* __restrict__ A,
                                                 const char* __restrict__ Bt,
                                                 const float* __restrict__ rowS,
                                                 const float* __restrict__ colS,
                                                 const float* __restrict__ bias,
                                                 char* __restrict__ outQ,
                                                 const unsigned short* __restrict__ resU,
                                                 float* __restrict__ outF) {
  __shared__ __align__(16) char lds[73728];
  const int tid = threadIdx.x;
  const int w = tid >> 6, lane = tid & 63;
  const int wm = w >> 2, wn = w & 3;            // 2x4 wave grid
  const int lrow = lane & 15, lg = lane >> 4;
  const int q8g = gridDim.x >> 3;
  const int wgid = (blockIdx.x & 7) * q8g + (blockIdx.x >> 3);
  const int row0 = (wgid / NCOL) * 128;
  const int col0 = (wgid % NCOL) * 128 * 2;     // BN=256

  // coalesced staging: lane q -> (row=q>>2, kc swizzled); chunk = 16 i8
  auto stageA = [&](int kt, int b) {
    const int r = tid >> 2, kc = swz_kc(tid, r);
    gload_lds16(A + (size_t)(row0 + r) * K + kt * 64 + kc * 16,
                lds + b * 8192 + tid * 16);
  };
  auto stageB = [&](int kt, int b) {
#pragma unroll
    for (int s = 0; s < 2; ++s) {
      const int q = s * 512 + tid;
      const int r = q >> 2, kc = swz_kc(q, r);
      gload_lds16(Bt + (size_t)(col0 + r) * K + kt * 64 + kc * 16,
                  lds + 24576 + b * 16384 + q * 16);
    }
  };

  const i32x4 zero4 = {0, 0, 0, 0};
  i32x4 acc[4][4];
#pragma unroll
  for (int m = 0; m < 4; ++m)
#pragma unroll
    for (int n = 0; n < 4; ++n) acc[m][n] = zero4;

  const int KT = K / 64;     // G3: 8, G4: 24

  stageA(0, 0); stageB(0, 0);
  stageA(1, 1); stageB(1, 1);
  asm volatile("s_waitcnt vmcnt(3)" ::: "memory");
  __builtin_amdgcn_s_barrier();

  int cur = 0;
  for (int t = 0; t < KT; ++t) {
    if (t + 2 < KT) {
      const int nb = (cur + 2 >= 3) ? cur - 1 : cur + 2;
      stageA(t + 2, nb); stageB(t + 2, nb);
    }
    const char* ab = lds + cur * 8192;
    const char* bb = lds + 24576 + cur * 16384;
    i32x4 av[4], bv[4];
#pragma unroll
    for (int mf = 0; mf < 4; ++mf) {
      const int ar = wm * 64 + mf * 16 + lrow;
      av[mf] = *(const i32x4*)(ab + (size_t)swz_rd(ar, lg) * 16);
    }
#pragma unroll
    for (int nf = 0; nf < 4; ++nf) {
      const int br = wn * 64 + nf * 16 + lrow;
      bv[nf] = *(const i32x4*)(bb + (size_t)swz_rd(br, lg) * 16);
    }
    __builtin_amdgcn_s_setprio(1);
#pragma unroll
    for (int mf = 0; mf < 4; ++mf)
#pragma unroll
      for (int nf = 0; nf < 4; ++nf)
        acc[mf][nf] = __builtin_amdgcn_mfma_i32_16x16x64_i8(av[mf], bv[nf],
                                                            acc[mf][nf], 0, 0, 0);
    __builtin_amdgcn_s_setprio(0);
    if (t + 2 < KT) { asm volatile("s_waitcnt vmcnt(3)" ::: "memory"); }
    else            { asm volatile("s_waitcnt vmcnt(0)" ::: "memory"); }
    __builtin_amdgcn_s_barrier();
    cur = (cur == 2) ? 0 : cur + 1;
  }

  if (EPI == 3) {
    const int kbase = col0 + (wn >> 1) * 128 + (wn & 1) * 64 + lrow * 4;
#pragma unroll
    for (int mf = 0; mf < 4; ++mf) {
      const int r0 = row0 + wm * 64 + mf * 16 + lg * 4;
      float rs4[4];
#pragma unroll
      for (int i = 0; i < 4; ++i) rs4[i] = rowS[r0 + i];
      float dsv[4], bbv[4];
#pragma unroll
      for (int nf = 0; nf < 4; ++nf) {
        const int c = col0 + wn * 64 + nf * 16 + lrow;
        dsv[nf] = colS[c];
        bbv[nf] = bias[c];
      }
#pragma unroll
      for (int i = 0; i < 4; ++i) {
        unsigned int pk = 0;
#pragma unroll
        for (int nf = 0; nf < 4; ++nf) {
          const float v = fmaf((float)acc[mf][nf][i], rs4[i] * dsv[nf], bbv[nf]);
          const float g = gelu_f(v);
          const unsigned int b =
              (unsigned int)(unsigned char)(char)q8i(fminf(fmaxf(g, -3.0f), 3.0f), IH1S);
          pk |= b << (8 * nf);
        }
        *(unsigned int*)&outQ[(size_t)(r0 + i) * N + kbase] = pk;
      }
    }
    return;
  }

  // EPI == 5 : 2-pass LDS bounce (128c x 128t f32, stride 132) -> coalesced stores
  float* fb = (float*)lds;
  const int bidx = row0 >> 12;
  const int t0 = row0 & 4095;
#pragma unroll
  for (int p = 0; p < 2; ++p) {
    if ((wn >> 1) == p) {
#pragma unroll
      for (int mf = 0; mf < 4; ++mf) {
        const int tl = wm * 64 + mf * 16 + lg * 4;
#pragma unroll
        for (int nf = 0; nf < 4; ++nf) {
          const int cl = (wn & 1) * 64 + nf * 16 + lrow;
          const int c = col0 + p * 128 + cl;
          const float ds = H1S * colS[c];
          const float bb = bias[c];
          f32x4 v;
#pragma unroll
          for (int i = 0; i < 4; ++i) v[i] = fmaf((float)acc[mf][nf][i], ds, bb);
          *(f32x4*)&fb[cl * 132 + tl] = v;
        }
      }
    }
    __syncthreads();
#pragma unroll
    for (int j = 0; j < 8; ++j) {
      const int cl = j * 16 + w * 2 + (lane >> 5);
      const int t = (lane & 31) * 4;
      const f32x4 v = *(const f32x4*)&fb[cl * 132 + t];
      const size_t addr = ((size_t)(bidx * C_ + col0 + p * 128 + cl)) * T_ + t0 + t;
      const us4 rv = *(const us4*)&resU[addr];
      f32x4 o;
#pragma unroll
      for (int i = 0; i < 4; ++i) o[i] = v[i] + bf2f(rv[i]);
      *(f32x4*)&outF[addr] = o;
    }
    __syncthreads();
  }
}

// ---------------- fused conv1d(k=7,p=3) + AdaLayerNorm -> int8 yln + per-token scale ----------------

__global__ __launch_bounds__(256) void convq_kernel(
    const unsigned short* __restrict__ rs,
    const float* __restrict__ dww,
    const float* __restrict__ dwb,
    const int* __restrict__ ids,
    const float* __restrict__ sce,
    const float* __restrict__ she,
    char* __restrict__ ylnq,
    float* __restrict__ yscale) {
  __shared__ float cbuf[16 * 520];
  const int tid = threadIdx.x;
  const int t0 = blockIdx.x * 16;
  const int b = blockIdx.y;
#pragma unroll
  for (int cc = 0; cc < 2; ++cc) {
    const int c = cc * 256 + tid;
    float f[24];
#pragma unroll
    for (int j = 0; j < 6; ++j) {
      const int t = t0 - 4 + j * 4;
      if (t >= 0 && t < T_) {
        const us4 v = *(const us4*)&rs[((size_t)(b * C_ + c)) * T_ + t];
#pragma unroll
        for (int i = 0; i < 4; ++i) f[j * 4 + i] = bf2f(v[i]);
      } else {
#pragma unroll
        for (int i = 0; i < 4; ++i) f[j * 4 + i] = 0.f;
      }
    }
    float wk[7];
#pragma unroll
    for (int k = 0; k < 7; ++k) wk[k] = dww[c * 7 + k];
    const float bb = dwb[c];
#pragma unroll
    for (int tt = 0; tt < 16; ++tt) {
      float s = bb;
#pragma unroll
      for (int k = 0; k < 7; ++k) s += f[tt + 1 + k] * wk[k];
      cbuf[tt * 520 + c] = s;
    }
  }
  __syncthreads();
  const int lane = tid & 63, w = tid >> 6;
  const int id = ids[b];
#pragma unroll
  for (int tt = 0; tt < 4; ++tt) {
    const int t = w * 4 + tt;
    const f32x4 v0 = *(const f32x4*)&cbuf[t * 520 + lane * 8];
    const f32x4 v1 = *(const f32x4*)&cbuf[t * 520 + lane * 8 + 4];
    float s = 0.f, sq = 0.f;
#pragma unroll
    for (int i = 0; i < 4; ++i) { s += v0[i]; sq += v0[i] * v0[i]; }
#pragma unroll
    for (int i = 0; i < 4; ++i) { s += v1[i]; sq += v1[i] * v1[i]; }
#pragma unroll
    for (int off = 1; off < 64; off <<= 1) {
      s += __shfl_xor(s, off);
      sq += __shfl_xor(sq, off);
    }
    const float mean = s * (1.0f / 512.0f);
    const float var = sq * (1.0f / 512.0f) - mean * mean;
    const float rstd = rsqrtf(var + 1e-6f);
    const f32x4 sc0 = *(const f32x4*)&sce[id * C_ + lane * 8];
    const f32x4 sc1 = *(const f32x4*)&sce[id * C_ + lane * 8 + 4];
    const f32x4 sh0 = *(const f32x4*)&she[id * C_ + lane * 8];
    const f32x4 sh1 = *(const f32x4*)&she[id * C_ + lane * 8 + 4];
    float y[8];
    float amax = 0.f;
#pragma unroll
    for (int i = 0; i < 4; ++i) {
      y[i]     = (v0[i] - mean) * rstd * sc0[i] + sh0[i];
      y[4 + i] = (v1[i] - mean) * rstd * sc1[i] + sh1[i];
    }
#pragma unroll
    for (int i = 0; i < 8; ++i) amax = fmaxf(amax, fabsf(y[i]));
#pragma unroll
    for (int off = 1; off < 64; off <<= 1) amax = fmaxf(amax, __shfl_xor(amax, off));
    amax = fmaxf(amax, 1e-20f);
    const float inv = 127.0f / amax;
    const int tg = b * T_ + t0 + t;
    char8v o;
#pragma unroll
    for (int i = 0; i < 8; ++i) o[i] = q8(y[i], inv);
    *(char8v*)&ylnq[(size_t)tg * C_ + lane * 8] = o;
    if (lane == 0) yscale[tg] = amax * (1.0f / 127.0f);
  }
}

// ---------------- launch ----------------

extern "C" void kernel_launch(void* const* d_in, const int* in_sizes, int n_in,
                              void* d_out, int out_size, void* d_ws, size_t ws_size,
                              hipStream_t stream) {
  const float* x   = (const float*)d_in[0];
  const int*   ids = (const int*)d_in[1];
  const float* Wq  = (const float*)d_in[2];
  const float* bq  = (const float*)d_in[3];
  const float* Wkv = (const float*)d_in[4];
  const float* bkv = (const float*)d_in[5];
  const float* Wo  = (const float*)d_in[6];
  const float* bo  = (const float*)d_in[7];
  const float* dww = (const float*)d_in[8];
  const float* dwb = (const float*)d_in[9];
  const float* sce = (const float*)d_in[10];
  const float* she = (const float*)d_in[11];
  const float* W1  = (const float*)d_in[12];
  const float* b1  = (const float*)d_in[13];
  const float* W2  = (const float*)d_in[14];
  const float* b2  = (const float*)d_in[15];
  const float* aux = (const float*)d_in[16];
  float* out = (float*)d_out;

  char* ws = (char*)d_ws;
  unsigned short* xt   = (unsigned short*)(ws + 0);              // 64 MB
  unsigned short* P    = (unsigned short*)(ws + (64u  << 20));   // 64 MB
  char*           ylnq = (char*)(ws + (64u << 20));              // 32 MB (overlays P; P dead)
  float*          ysc  = (float*)(ws + (100u << 20));            // 256 KB
  unsigned short* rs   = (unsigned short*)(ws + (128u << 20));   // 64 MB (bf16)
  char*           H1Q  = (char*)(ws + (192u << 20));             // 96 MB (i8)
  char* sm = ws + (384u << 20);
  float*          kv   = (float*)(sm);                           // 256 KB
  float*          cb   = (float*)(sm + 262144);                  // 2 KB
  unsigned short* MT   = (unsigned short*)(sm + 264192);         // 512 KB
  unsigned short* VoT  = (unsigned short*)(sm + 788480);         // 512 KB
  char*           W1Q  = (char*)(sm + 1312768);                  // 768 KB
  char*           W2Q  = (char*)(sm + 2099200);                  // 768 KB
  float*          w1s  = (float*)(sm + 2885632);                 // 6 KB
  float*          w2s  = (float*)(sm + 2891776);                 // 2 KB

  pre_a<<<dim3(2304), dim3(256), 0, stream>>>(aux, Wkv, bkv, W1, W2, kv, w1s, w2s);
  pre_b<<<dim3(7168), dim3(256), 0, stream>>>(Wq, bq, Wo, kv, W1, W2, w1s, w2s,
                                              MT, cb, VoT, W1Q, W2Q);
  xt_kernel<<<dim3(64, 8, 16), dim3(256), 0, stream>>>(x, xt);

  // attention as two m97-structure GEMMs with packed/bounced epilogues
  gemm_mfma<512, 512, 4, 1><<<dim3(2048), dim3(256), 0, stream>>>(
      xt, MT, cb, P, nullptr, nullptr);
  gemm_mfma<512, 512, 4, 4><<<dim3(2048), dim3(256), 0, stream>>>(
      P, VoT, bo, rs, xt, nullptr);
  convq_kernel<<<dim3(256, 16), dim3(256), 0, stream>>>(rs, dww, dwb, ids, sce, she,
                                                        ylnq, ysc);
  // MLP as two int8 8-wave GEMMs, coalesced staging + swizzled LDS chunks
  gemm8w<1536, 512, 6, 3><<<dim3(3072), dim3(512), 0, stream>>>(
      ylnq, W1Q, ysc, w1s, b1, H1Q, nullptr, nullptr);
  gemm8w<512, 1536, 2, 5><<<dim3(1024), dim3(512), 0, stream>>>(
      H1Q, W2Q, nullptr, w2s, b2, nullptr, rs, out);
}

// Round 19
// 532.615 us; speedup vs baseline: 1.3742x; 1.0246x over previous
//
#include <hip/hip_runtime.h>
#include <hip/hip_bf16.h>
#include <math.h>

#define B_ 16
#define C_ 512
#define T_ 4096
#define I_ 1536

typedef short short8 __attribute__((ext_vector_type(8)));
typedef unsigned short ushort8 __attribute__((ext_vector_type(8)));
typedef unsigned short us4 __attribute__((ext_vector_type(4)));
typedef float f32x4 __attribute__((ext_vector_type(4)));
typedef int i32x4 __attribute__((ext_vector_type(4)));
typedef char char8v __attribute__((ext_vector_type(8)));

static __device__ __forceinline__ unsigned short f2bf(float f) {
  union { float f; unsigned int u; } v; v.f = f;
  unsigned int r = v.u + 0x7fffu + ((v.u >> 16) & 1u);
  return (unsigned short)(r >> 16);
}
static __device__ __forceinline__ float bf2f(unsigned short h) {
  union { unsigned int u; float f; } v; v.u = ((unsigned int)h) << 16;
  return v.f;
}

static __device__ __forceinline__ float fast_rcp(float x) {
  float r; asm("v_rcp_f32 %0, %1" : "=v"(r) : "v"(x)); return r;
}

// tanh-form GELU. |err vs erf| <= ~3e-3/elem, diluted by @W2.
static __device__ __forceinline__ float gelu_f(float v) {
  const float v2 = v * v;
  const float w = v * (0.7978845608f + 0.0356774081f * v2);
  const float a = fminf(w * 2.8853900818f, 126.0f);
  const float u = exp2f(a);
  return v * u * fast_rcp(u + 1.0f);
}

static __device__ __forceinline__ int q8i(float v, float inv) {
  int q = __float2int_rn(v * inv);
  q = q > 127 ? 127 : (q < -127 ? -127 : q);
  return q;
}
static __device__ __forceinline__ char q8(float v, float inv) {
  return (char)q8i(v, inv);
}

__device__ __forceinline__ void gload_lds16(const void* g, void* l) {
  __builtin_amdgcn_global_load_lds((const __attribute__((address_space(1))) void*)g,
                                   (__attribute__((address_space(3))) void*)l, 16, 0, 0);
}

#define H1S   (3.0f / 127.0f)
#define IH1S  (127.0f / 3.0f)

// kappa-permutation within each 128-col block
static __device__ __forceinline__ int kappa_to_c(int k128) {
  const int wcbit = k128 >> 6, lrow = (k128 & 63) >> 2, n = k128 & 3;
  return wcbit * 64 + n * 16 + lrow;
}

// 4-chunk staging swizzle (64B rows, i8 BK=64 / bf16 BK=32)
static __device__ __forceinline__ int swz_kc(int q, int row) {
  return (q & 3) ^ ((row >> 1) & 3);
}
static __device__ __forceinline__ int swz_rd(int row, int lg) {
  return row * 4 + (lg ^ ((row >> 1) & 3));
}
// 8-chunk staging swizzle (128B rows, bf16 BK=64): bank group = phys chunk only
static __device__ __forceinline__ int swz8_kc(int q, int row) {
  return (q & 7) ^ ((row >> 1) & 7);
}
static __device__ __forceinline__ int swz8_rd(int row, int chunk) {
  return row * 8 + (chunk ^ ((row >> 1) & 7));
}

// ---------------- precompute stage A: kv + weight scales ----------------

__global__ __launch_bounds__(256) void pre_a(const float* __restrict__ aux,
                                             const float* __restrict__ Wkv,
                                             const float* __restrict__ bkv,
                                             const float* __restrict__ W1,
                                             const float* __restrict__ W2,
                                             float* __restrict__ kv,
                                             float* __restrict__ w1s,
                                             float* __restrict__ w2s) {
  __shared__ unsigned int red;
  const int bid = blockIdx.x;
  const int tid = threadIdx.x;
  if (bid < 256) {
    const int g = bid * 256 + tid;              // 65536 = 64 * 1024
    const int j = g >> 10, cc = g & 1023;
    float s = bkv[cc];
    for (int i = 0; i < C_; ++i) s += aux[j * C_ + i] * Wkv[i * (2 * C_) + cc];
    kv[g] = s;
    return;
  }
  const bool isW1 = bid < 256 + 1536;
  const int n = isW1 ? (bid - 256) : (bid - 256 - 1536);
  const int ROWS = isW1 ? 512 : 1536;
  const int NC   = isW1 ? 1536 : 512;
  const float* W = isW1 ? W1 : W2;
  if (tid == 0) red = 0;
  __syncthreads();
  float amax = 0.f;
  for (int k = tid; k < ROWS; k += 256)
    amax = fmaxf(amax, fabsf(W[(size_t)k * NC + n]));
#pragma unroll
  for (int off = 1; off < 64; off <<= 1)
    amax = fmaxf(amax, __shfl_xor(amax, off));
  if ((tid & 63) == 0) atomicMax(&red, __float_as_uint(amax));
  __syncthreads();
  if (tid == 0) (isW1 ? w1s : w2s)[n] = fmaxf(__uint_as_float(red), 1e-20f) / 127.0f;
}

// ---------------- precompute stage B: MT, cb, VoT(kappa), W1Q, W2Q(kappa) ----------------

__global__ __launch_bounds__(256) void pre_b(const float* __restrict__ Wq,
                                             const float* __restrict__ bq,
                                             const float* __restrict__ Wo,
                                             const float* __restrict__ kv,
                                             const float* __restrict__ W1,
                                             const float* __restrict__ W2,
                                             const float* __restrict__ w1s,
                                             const float* __restrict__ w2s,
                                             unsigned short* __restrict__ MT,
                                             float* __restrict__ cbias,
                                             unsigned short* __restrict__ VoT,
                                             char* __restrict__ W1Q,
                                             char* __restrict__ W2Q) {
  const int bid = blockIdx.x;
  const int tid = threadIdx.x;
  if (bid < 512) {
    const int col = bid;
    const int h = col >> 6, j = col & 63;
    const float* kvp = kv + j * 1024 + h * 64;
    for (int c = tid; c < C_; c += 256) {
      float s = 0.f;
      for (int d = 0; d < 64; ++d) s += Wq[(size_t)c * C_ + h * 64 + d] * kvp[d];
      MT[(size_t)col * C_ + c] = f2bf(0.125f * s);
    }
    if (tid == 0) {
      float s = 0.f;
      for (int d = 0; d < 64; ++d) s += bq[h * 64 + d] * kvp[d];
      cbias[col] = 0.125f * s;
    }
  } else if (bid < 1024) {
    const int cp = bid - 512;
    for (int k = tid; k < 512; k += 256) {
      const int c = (k >> 7) * 128 + kappa_to_c(k & 127);   // true attention col
      const int h = c >> 6, j = c & 63;
      float s = 0.f;
      for (int d = 0; d < 64; ++d)
        s += kv[j * 1024 + 512 + h * 64 + d] * Wo[(size_t)(h * 64 + d) * C_ + cp];
      VoT[(size_t)cp * 512 + k] = f2bf(s);
    }
  } else if (bid < 4096) {
    const int g = (bid - 1024) * 256 + tid;      // 1536*512
    const int n = g >> 9, k = g & 511;
    W1Q[g] = q8(W1[(size_t)k * I_ + n], 1.0f / w1s[n]);
  } else {
    const int g = (bid - 4096) * 256 + tid;      // 512*1536 : W2Q[n][k] kappa-order
    const int n = g / 1536, k = g - n * 1536;
    const int c = (k >> 7) * 128 + kappa_to_c(k & 127);     // true I-channel
    W2Q[g] = q8(W2[(size_t)c * C_ + n], 1.0f / w2s[n]);
  }
}

// ---------------- x (B,C,T) -> xt bf16 (B*T, C), vectorized stores ----------------

__global__ __launch_bounds__(256) void xt_kernel(const float* __restrict__ x,
                                                 unsigned short* __restrict__ xt) {
  __shared__ float ld[64][65];
  const int tid = threadIdx.x;
  const int t0 = blockIdx.x * 64, c0 = blockIdx.y * 64, b = blockIdx.z;
  for (int idx = tid; idx < 4096; idx += 256) {
    const int r = idx >> 6, cc = idx & 63;
    ld[r][cc] = x[((size_t)(b * C_ + c0 + r)) * T_ + t0 + cc];
  }
  __syncthreads();
#pragma unroll
  for (int s = 0; s < 2; ++s) {
    const int idx = s * 256 + tid;      // 512 = 64 t-rows x 8 col-chunks
    const int tr = idx >> 3, cl8 = (idx & 7) * 8;
    ushort8 o;
#pragma unroll
    for (int qv = 0; qv < 8; ++qv) o[qv] = f2bf(ld[cl8 + qv][tr]);
    *(ushort8*)&xt[((size_t)(b * T_ + t0 + tr)) * C_ + c0 + cl8] = o;
  }
}

// ---------------- GEMM A (m97, BK=64, 8-chunk coalesced swizzled staging) ----------------
// EPI 1: softmax epilogue, P stored kappa-packed (ushort4 per (m,i)).
// EPI 4: LDS-bounce [c][t] bf16 tile (aliases dead lA/lB) -> coalesced ushort8 stores.
template<int N, int K, int NCOL, int EPI>
__global__ __launch_bounds__(256) void gemm_mfma(const unsigned short* __restrict__ A,
                                                 const unsigned short* __restrict__ Bt,
                                                 const float* __restrict__ bias,
                                                 unsigned short* __restrict__ outU,
                                                 const unsigned short* __restrict__ resU,
                                                 float* __restrict__ outF) {
  __shared__ __align__(16) unsigned short shm[EPI == 4 ? 128 * 132 : 128 * 128];
  unsigned short* lA = shm;              // 128 rows x 64 k (8 chunks/row)
  unsigned short* lB = shm + 128 * 64;
  unsigned short* bounce = shm;          // EPI4 only, after K-loop (lA/lB dead)
  const int q = gridDim.x >> 3;
  const int wgid = (blockIdx.x & 7) * q + (blockIdx.x >> 3);
  const int row0 = (wgid / NCOL) * 128;
  const int col0 = (wgid % NCOL) * 128;
  const int tid = threadIdx.x;
  const int w = tid >> 6, lane = tid & 63;
  const int wr = (w >> 1) * 64, wc = (w & 1) * 64;

  const f32x4 zero4 = {0.f, 0.f, 0.f, 0.f};
  f32x4 acc[4][4];
#pragma unroll
  for (int m = 0; m < 4; ++m)
#pragma unroll
    for (int n = 0; n < 4; ++n) acc[m][n] = zero4;

  const size_t aBase = (size_t)row0 * K;
  const size_t bBase = (size_t)col0 * K;
  const int lrow = lane & 15, lg = lane >> 4;

  for (int k0 = 0; k0 < K; k0 += 64) {
#pragma unroll
    for (int s = 0; s < 4; ++s) {
      const int qq = s * 256 + tid;      // 1024 chunks per operand
      const int r = qq >> 3;
      const int kc = swz8_kc(qq, r);
      gload_lds16(A + aBase + (size_t)r * K + k0 + kc * 8, (char*)lA + qq * 16);
      gload_lds16(Bt + bBase + (size_t)r * K + k0 + kc * 8, (char*)lB + qq * 16);
    }
    __syncthreads();
    short8 av[2][4], bv[2][4];
#pragma unroll
    for (int ks = 0; ks < 2; ++ks) {
      const int ch = ks * 4 + lg;
#pragma unroll
      for (int m = 0; m < 4; ++m) {
        const int ar = wr + m * 16 + lrow;
        av[ks][m] = *(const short8*)&lA[swz8_rd(ar, ch) * 8];
        const int br = wc + m * 16 + lrow;
        bv[ks][m] = *(const short8*)&lB[swz8_rd(br, ch) * 8];
      }
    }
#pragma unroll
    for (int ks = 0; ks < 2; ++ks)
#pragma unroll
      for (int m = 0; m < 4; ++m)
#pragma unroll
        for (int n = 0; n < 4; ++n)
          acc[m][n] = __builtin_amdgcn_mfma_f32_16x16x32_bf16(av[ks][m], bv[ks][n],
                                                              acc[m][n], 0, 0, 0);
    __syncthreads();
  }

  if (EPI == 1) {
    float cbv[4];
#pragma unroll
    for (int n = 0; n < 4; ++n) cbv[n] = bias[col0 + wc + n * 16 + lrow];
    const int kbase = col0 + wc + lrow * 4;     // kappa address of this thread's 4 cols
#pragma unroll
    for (int m = 0; m < 4; ++m) {
#pragma unroll
      for (int i = 0; i < 4; ++i) {
        float e0 = acc[m][0][i] + cbv[0];
        float e1 = acc[m][1][i] + cbv[1];
        float e2 = acc[m][2][i] + cbv[2];
        float e3 = acc[m][3][i] + cbv[3];
        float mx = fmaxf(fmaxf(e0, e1), fmaxf(e2, e3));
        mx = fmaxf(mx, __shfl_xor(mx, 1));
        mx = fmaxf(mx, __shfl_xor(mx, 2));
        mx = fmaxf(mx, __shfl_xor(mx, 4));
        mx = fmaxf(mx, __shfl_xor(mx, 8));
        e0 = __expf(e0 - mx); e1 = __expf(e1 - mx);
        e2 = __expf(e2 - mx); e3 = __expf(e3 - mx);
        float s = e0 + e1 + e2 + e3;
        s += __shfl_xor(s, 1);
        s += __shfl_xor(s, 2);
        s += __shfl_xor(s, 4);
        s += __shfl_xor(s, 8);
        const float inv = 1.0f / s;
        us4 pk;
        pk[0] = f2bf(e0 * inv); pk[1] = f2bf(e1 * inv);
        pk[2] = f2bf(e2 * inv); pk[3] = f2bf(e3 * inv);
        *(us4*)&outU[(size_t)(row0 + wr + m * 16 + lg * 4 + i) * N + kbase] = pk;
      }
    }
    return;
  }

  // EPI == 4 : residual epilogue with LDS transpose bounce
#pragma unroll
  for (int m = 0; m < 4; ++m) {
    const int r0 = row0 + wr + m * 16 + (lg << 2);
    const int tl = wr + m * 16 + (lg << 2);
#pragma unroll
    for (int n = 0; n < 4; ++n) {
      const int cl = wc + n * 16 + lrow;
      const int c = col0 + cl;
      const float bb = bias[c];
      us4 pk;
#pragma unroll
      for (int i = 0; i < 4; ++i)
        pk[i] = f2bf(bf2f(resU[(size_t)(r0 + i) * 512 + c]) + acc[m][n][i] + bb);
      *(us4*)&bounce[cl * 132 + tl] = pk;
    }
  }
  __syncthreads();
  const int bidx = row0 >> 12;
  const int t0 = row0 & 4095;
#pragma unroll
  for (int j = 0; j < 8; ++j) {
    const int cl = j * 16 + w * 4 + (lane >> 4);
    const int t = (lane & 15) * 8;
    const ushort8 v = *(const ushort8*)&bounce[cl * 132 + t];
    *(ushort8*)&outU[((size_t)(bidx * C_ + col0 + cl)) * T_ + t0 + t] = v;
  }
}

// ---------------- GEMM B: int8, 8 waves, 128x256 tile, BK=64, 3-buf, coalesced staging ------
template<int N, int K, int NCOL, int EPI>
__global__ __launch_bounds__(512, 4) void gemm8w(const char* __restrict__ A,
                                                 const char* __restrict__ Bt,
                                                 const float* __restrict__ rowS,
                                                 const float* __restrict__ colS,
                                                 const float* __restrict__ bias,
                                                 char* __restrict__ outQ,
                                                 const unsigned short* __restrict__ resU,
                                                 float* __restrict__ outF) {
  __shared__ __align__(16) char lds[73728];
  const int tid = threadIdx.x;
  const int w = tid >> 6, lane = tid & 63;
  const int wm = w >> 2, wn = w & 3;            // 2x4 wave grid
  const int lrow = lane & 15, lg = lane >> 4;
  const int q8g = gridDim.x >> 3;
  const int wgid = (blockIdx.x & 7) * q8g + (blockIdx.x >> 3);
  const int row0 = (wgid / NCOL) * 128;
  const int col0 = (wgid % NCOL) * 128 * 2;     // BN=256

  auto stageA = [&](int kt, int b) {
    const int r = tid >> 2, kc = swz_kc(tid, r);
    gload_lds16(A + (size_t)(row0 + r) * K + kt * 64 + kc * 16,
                lds + b * 8192 + tid * 16);
  };
  auto stageB = [&](int kt, int b) {
#pragma unroll
    for (int s = 0; s < 2; ++s) {
      const int q = s * 512 + tid;
      const int r = q >> 2, kc = swz_kc(q, r);
      gload_lds16(Bt + (size_t)(col0 + r) * K + kt * 64 + kc * 16,
                  lds + 24576 + b * 16384 + q * 16);
    }
  };

  const i32x4 zero4 = {0, 0, 0, 0};
  i32x4 acc[4][4];
#pragma unroll
  for (int m = 0; m < 4; ++m)
#pragma unroll
    for (int n = 0; n < 4; ++n) acc[m][n] = zero4;

  const int KT = K / 64;     // G3: 8, G4: 24

  stageA(0, 0); stageB(0, 0);
  stageA(1, 1); stageB(1, 1);
  asm volatile("s_waitcnt vmcnt(3)" ::: "memory");
  __builtin_amdgcn_s_barrier();

  int cur = 0;
  for (int t = 0; t < KT; ++t) {
    if (t + 2 < KT) {
      const int nb = (cur + 2 >= 3) ? cur - 1 : cur + 2;
      stageA(t + 2, nb); stageB(t + 2, nb);
    }
    const char* ab = lds + cur * 8192;
    const char* bb = lds + 24576 + cur * 16384;
    i32x4 av[4], bv[4];
#pragma unroll
    for (int mf = 0; mf < 4; ++mf) {
      const int ar = wm * 64 + mf * 16 + lrow;
      av[mf] = *(const i32x4*)(ab + (size_t)swz_rd(ar, lg) * 16);
    }
#pragma unroll
    for (int nf = 0; nf < 4; ++nf) {
      const int br = wn * 64 + nf * 16 + lrow;
      bv[nf] = *(const i32x4*)(bb + (size_t)swz_rd(br, lg) * 16);
    }
    __builtin_amdgcn_s_setprio(1);
#pragma unroll
    for (int mf = 0; mf < 4; ++mf)
#pragma unroll
      for (int nf = 0; nf < 4; ++nf)
        acc[mf][nf] = __builtin_amdgcn_mfma_i32_16x16x64_i8(av[mf], bv[nf],
                                                            acc[mf][nf], 0, 0, 0);
    __builtin_amdgcn_s_setprio(0);
    if (t + 2 < KT) { asm volatile("s_waitcnt vmcnt(3)" ::: "memory"); }
    else            { asm volatile("s_waitcnt vmcnt(0)" ::: "memory"); }
    __builtin_amdgcn_s_barrier();
    cur = (cur == 2) ? 0 : cur + 1;
  }

  if (EPI == 3) {
    const int kbase = col0 + (wn >> 1) * 128 + (wn & 1) * 64 + lrow * 4;
#pragma unroll
    for (int mf = 0; mf < 4; ++mf) {
      const int r0 = row0 + wm * 64 + mf * 16 + lg * 4;
      float rs4[4];
#pragma unroll
      for (int i = 0; i < 4; ++i) rs4[i] = rowS[r0 + i];
      float dsv[4], bbv[4];
#pragma unroll
      for (int nf = 0; nf < 4; ++nf) {
        const int c = col0 + wn * 64 + nf * 16 + lrow;
        dsv[nf] = colS[c];
        bbv[nf] = bias[c];
      }
#pragma unroll
      for (int i = 0; i < 4; ++i) {
        unsigned int pk = 0;
#pragma unroll
        for (int nf = 0; nf < 4; ++nf) {
          const float v = fmaf((float)acc[mf][nf][i], rs4[i] * dsv[nf], bbv[nf]);
          const float g = gelu_f(v);
          const unsigned int b =
              (unsigned int)(unsigned char)(char)q8i(fminf(fmaxf(g, -3.0f), 3.0f), IH1S);
          pk |= b << (8 * nf);
        }
        *(unsigned int*)&outQ[(size_t)(r0 + i) * N + kbase] = pk;
      }
    }
    return;
  }

  // EPI == 5 : 2-pass LDS bounce (128c x 128t f32, stride 132) -> coalesced stores
  float* fb = (float*)lds;
  const int bidx = row0 >> 12;
  const int t0 = row0 & 4095;
#pragma unroll
  for (int p = 0; p < 2; ++p) {
    if ((wn >> 1) == p) {
#pragma unroll
      for (int mf = 0; mf < 4; ++mf) {
        const int tl = wm * 64 + mf * 16 + lg * 4;
#pragma unroll
        for (int nf = 0; nf < 4; ++nf) {
          const int cl = (wn & 1) * 64 + nf * 16 + lrow;
          const int c = col0 + p * 128 + cl;
          const float ds = H1S * colS[c];
          const float bb = bias[c];
          f32x4 v;
#pragma unroll
          for (int i = 0; i < 4; ++i) v[i] = fmaf((float)acc[mf][nf][i], ds, bb);
          *(f32x4*)&fb[cl * 132 + tl] = v;
        }
      }
    }
    __syncthreads();
#pragma unroll
    for (int j = 0; j < 8; ++j) {
      const int cl = j * 16 + w * 2 + (lane >> 5);
      const int t = (lane & 31) * 4;
      const f32x4 v = *(const f32x4*)&fb[cl * 132 + t];
      const size_t addr = ((size_t)(bidx * C_ + col0 + p * 128 + cl)) * T_ + t0 + t;
      const us4 rv = *(const us4*)&resU[addr];
      f32x4 o;
#pragma unroll
      for (int i = 0; i < 4; ++i) o[i] = v[i] + bf2f(rv[i]);
      *(f32x4*)&outF[addr] = o;
    }
    __syncthreads();
  }
}

// ---------------- fused conv1d(k=7,p=3) + AdaLayerNorm -> int8 yln + per-token scale --------
// 8-t blocks; rs window (16t x 512c) LDS-staged with t-fastest chunks (coalesced).

__global__ __launch_bounds__(256) void convq_kernel(
    const unsigned short* __restrict__ rs,
    const float* __restrict__ dww,
    const float* __restrict__ dwb,
    const int* __restrict__ ids,
    const float* __restrict__ sce,
    const float* __restrict__ she,
    char* __restrict__ ylnq,
    float* __restrict__ yscale) {
  __shared__ unsigned short rbuf[512 * 28];   // [c][16t window + pad], stride 28 hw
  __shared__ float cbuf[8 * 520];
  const int tid = threadIdx.x;
  const int t0 = blockIdx.x * 8;
  const int b = blockIdx.y;
  const int w0 = t0 - 4;                      // window [w0, w0+16)
  // stage: 2048 us4-chunks (4t each); 4 consecutive lanes cover one channel's 32B
#pragma unroll
  for (int s = 0; s < 8; ++s) {
    const int f = s * 256 + tid;
    const int c = f >> 2, j = f & 3;
    const int t = w0 + j * 4;
    us4 v = {0, 0, 0, 0};
    if (t >= 0 && t + 3 < T_) {
      v = *(const us4*)&rs[((size_t)(b * C_ + c)) * T_ + t];
    } else {
#pragma unroll
      for (int e = 0; e < 4; ++e)
        if (t + e >= 0 && t + e < T_) v[e] = rs[((size_t)(b * C_ + c)) * T_ + t + e];
    }
    *(us4*)&rbuf[c * 28 + j * 4] = v;
  }
  __syncthreads();
#pragma unroll
  for (int cc = 0; cc < 2; ++cc) {
    const int c = cc * 256 + tid;
    float f[15];
#pragma unroll
    for (int i = 0; i < 15; ++i) f[i] = bf2f(rbuf[c * 28 + i]);
    float wk[7];
#pragma unroll
    for (int k = 0; k < 7; ++k) wk[k] = dww[c * 7 + k];
    const float bb = dwb[c];
#pragma unroll
    for (int tt = 0; tt < 8; ++tt) {
      float s = bb;
#pragma unroll
      for (int k = 0; k < 7; ++k) s += f[tt + 1 + k] * wk[k];
      cbuf[tt * 520 + c] = s;
    }
  }
  __syncthreads();
  const int lane = tid & 63, w = tid >> 6;
  const int id = ids[b];
#pragma unroll
  for (int tt = 0; tt < 2; ++tt) {
    const int t = w * 2 + tt;
    const f32x4 v0 = *(const f32x4*)&cbuf[t * 520 + lane * 8];
    const f32x4 v1 = *(const f32x4*)&cbuf[t * 520 + lane * 8 + 4];
    float s = 0.f, sq = 0.f;
#pragma unroll
    for (int i = 0; i < 4; ++i) { s += v0[i]; sq += v0[i] * v0[i]; }
#pragma unroll
    for (int i = 0; i < 4; ++i) { s += v1[i]; sq += v1[i] * v1[i]; }
#pragma unroll
    for (int off = 1; off < 64; off <<= 1) {
      s += __shfl_xor(s, off);
      sq += __shfl_xor(sq, off);
    }
    const float mean = s * (1.0f / 512.0f);
    const float var = sq * (1.0f / 512.0f) - mean * mean;
    const float rstd = rsqrtf(var + 1e-6f);
    const f32x4 sc0 = *(const f32x4*)&sce[id * C_ + lane * 8];
    const f32x4 sc1 = *(const f32x4*)&sce[id * C_ + lane * 8 + 4];
    const f32x4 sh0 = *(const f32x4*)&she[id * C_ + lane * 8];
    const f32x4 sh1 = *(const f32x4*)&she[id * C_ + lane * 8 + 4];
    float y[8];
    float amax = 0.f;
#pragma unroll
    for (int i = 0; i < 4; ++i) {
      y[i]     = (v0[i] - mean) * rstd * sc0[i] + sh0[i];
      y[4 + i] = (v1[i] - mean) * rstd * sc1[i] + sh1[i];
    }
#pragma unroll
    for (int i = 0; i < 8; ++i) amax = fmaxf(amax, fabsf(y[i]));
#pragma unroll
    for (int off = 1; off < 64; off <<= 1) amax = fmaxf(amax, __shfl_xor(amax, off));
    amax = fmaxf(amax, 1e-20f);
    const float inv = 127.0f / amax;
    const int tg = b * T_ + t0 + t;
    char8v o;
#pragma unroll
    for (int i = 0; i < 8; ++i) o[i] = q8(y[i], inv);
    *(char8v*)&ylnq[(size_t)tg * C_ + lane * 8] = o;
    if (lane == 0) yscale[tg] = amax * (1.0f / 127.0f);
  }
}

// ---------------- launch ----------------

extern "C" void kernel_launch(void* const* d_in, const int* in_sizes, int n_in,
                              void* d_out, int out_size, void* d_ws, size_t ws_size,
                              hipStream_t stream) {
  const float* x   = (const float*)d_in[0];
  const int*   ids = (const int*)d_in[1];
  const float* Wq  = (const float*)d_in[2];
  const float* bq  = (const float*)d_in[3];
  const float* Wkv = (const float*)d_in[4];
  const float* bkv = (const float*)d_in[5];
  const float* Wo  = (const float*)d_in[6];
  const float* bo  = (const float*)d_in[7];
  const float* dww = (const float*)d_in[8];
  const float* dwb = (const float*)d_in[9];
  const float* sce = (const float*)d_in[10];
  const float* she = (const float*)d_in[11];
  const float* W1  = (const float*)d_in[12];
  const float* b1  = (const float*)d_in[13];
  const float* W2  = (const float*)d_in[14];
  const float* b2  = (const float*)d_in[15];
  const float* aux = (const float*)d_in[16];
  float* out = (float*)d_out;

  char* ws = (char*)d_ws;
  unsigned short* xt   = (unsigned short*)(ws + 0);              // 64 MB
  unsigned short* P    = (unsigned short*)(ws + (64u  << 20));   // 64 MB
  char*           ylnq = (char*)(ws + (64u << 20));              // 32 MB (overlays P; P dead)
  float*          ysc  = (float*)(ws + (100u << 20));            // 256 KB
  unsigned short* rs   = (unsigned short*)(ws + (128u << 20));   // 64 MB (bf16)
  char*           H1Q  = (char*)(ws + (192u << 20));             // 96 MB (i8)
  char* sm = ws + (384u << 20);
  float*          kv   = (float*)(sm);                           // 256 KB
  float*          cb   = (float*)(sm + 262144);                  // 2 KB
  unsigned short* MT   = (unsigned short*)(sm + 264192);         // 512 KB
  unsigned short* VoT  = (unsigned short*)(sm + 788480);         // 512 KB
  char*           W1Q  = (char*)(sm + 1312768);                  // 768 KB
  char*           W2Q  = (char*)(sm + 2099200);                  // 768 KB
  float*          w1s  = (float*)(sm + 2885632);                 // 6 KB
  float*          w2s  = (float*)(sm + 2891776);                 // 2 KB

  pre_a<<<dim3(2304), dim3(256), 0, stream>>>(aux, Wkv, bkv, W1, W2, kv, w1s, w2s);
  pre_b<<<dim3(7168), dim3(256), 0, stream>>>(Wq, bq, Wo, kv, W1, W2, w1s, w2s,
                                              MT, cb, VoT, W1Q, W2Q);
  xt_kernel<<<dim3(64, 8, 16), dim3(256), 0, stream>>>(x, xt);

  // attention as two BK=64 m97-structure GEMMs with packed/bounced epilogues
  gemm_mfma<512, 512, 4, 1><<<dim3(2048), dim3(256), 0, stream>>>(
      xt, MT, cb, P, nullptr, nullptr);
  gemm_mfma<512, 512, 4, 4><<<dim3(2048), dim3(256), 0, stream>>>(
      P, VoT, bo, rs, xt, nullptr);
  convq_kernel<<<dim3(512, 16), dim3(256), 0, stream>>>(rs, dww, dwb, ids, sce, she,
                                                        ylnq, ysc);
  // MLP as two int8 8-wave GEMMs, coalesced staging + swizzled LDS chunks
  gemm8w<1536, 512, 6, 3><<<dim3(3072), dim3(512), 0, stream>>>(
      ylnq, W1Q, ysc, w1s, b1, H1Q, nullptr, nullptr);
  gemm8w<512, 1536, 2, 5><<<dim3(1024), dim3(512), 0, stream>>>(
      H1Q, W2Q, nullptr, w2s, b2, nullptr, rs, out);
}

// Round 20
// 526.891 us; speedup vs baseline: 1.3891x; 1.0109x over previous
//
#include <hip/hip_runtime.h>
#include <hip/hip_bf16.h>
#include <math.h>

#define B_ 16
#define C_ 512
#define T_ 4096
#define I_ 1536

typedef short short8 __attribute__((ext_vector_type(8)));
typedef unsigned short ushort8 __attribute__((ext_vector_type(8)));
typedef unsigned short us4 __attribute__((ext_vector_type(4)));
typedef float f32x4 __attribute__((ext_vector_type(4)));
typedef int i32x4 __attribute__((ext_vector_type(4)));
typedef char char8v __attribute__((ext_vector_type(8)));

static __device__ __forceinline__ unsigned short f2bf(float f) {
  union { float f; unsigned int u; } v; v.f = f;
  unsigned int r = v.u + 0x7fffu + ((v.u >> 16) & 1u);
  return (unsigned short)(r >> 16);
}
static __device__ __forceinline__ float bf2f(unsigned short h) {
  union { unsigned int u; float f; } v; v.u = ((unsigned int)h) << 16;
  return v.f;
}

static __device__ __forceinline__ float fast_rcp(float x) {
  float r; asm("v_rcp_f32 %0, %1" : "=v"(r) : "v"(x)); return r;
}

// tanh-form GELU. |err vs erf| <= ~3e-3/elem, diluted by @W2.
static __device__ __forceinline__ float gelu_f(float v) {
  const float v2 = v * v;
  const float w = v * (0.7978845608f + 0.0356774081f * v2);
  const float a = fminf(w * 2.8853900818f, 126.0f);
  const float u = exp2f(a);
  return v * u * fast_rcp(u + 1.0f);
}

static __device__ __forceinline__ int q8i(float v, float inv) {
  int q = __float2int_rn(v * inv);
  q = q > 127 ? 127 : (q < -127 ? -127 : q);
  return q;
}
static __device__ __forceinline__ char q8(float v, float inv) {
  return (char)q8i(v, inv);
}

__device__ __forceinline__ void gload_lds16(const void* g, void* l) {
  __builtin_amdgcn_global_load_lds((const __attribute__((address_space(1))) void*)g,
                                   (__attribute__((address_space(3))) void*)l, 16, 0, 0);
}

#define H1S   (3.0f / 127.0f)
#define IH1S  (127.0f / 3.0f)

// kappa-permutation within each 128-col block
static __device__ __forceinline__ int kappa_to_c(int k128) {
  const int wcbit = k128 >> 6, lrow = (k128 & 63) >> 2, n = k128 & 3;
  return wcbit * 64 + n * 16 + lrow;
}

// 4-chunk staging swizzle (64B rows)
static __device__ __forceinline__ int swz_kc(int q, int row) {
  return (q & 3) ^ ((row >> 1) & 3);
}
static __device__ __forceinline__ int swz_rd(int row, int lg) {
  return row * 4 + (lg ^ ((row >> 1) & 3));
}
// 8-chunk staging swizzle (128B rows, bf16 BK=64)
static __device__ __forceinline__ int swz8_kc(int q, int row) {
  return (q & 7) ^ ((row >> 1) & 7);
}
static __device__ __forceinline__ int swz8_rd(int row, int chunk) {
  return row * 8 + (chunk ^ ((row >> 1) & 7));
}

// ---------------- precompute stage A: kv + weight scales ----------------

__global__ __launch_bounds__(256) void pre_a(const float* __restrict__ aux,
                                             const float* __restrict__ Wkv,
                                             const float* __restrict__ bkv,
                                             const float* __restrict__ W1,
                                             const float* __restrict__ W2,
                                             float* __restrict__ kv,
                                             float* __restrict__ w1s,
                                             float* __restrict__ w2s) {
  __shared__ unsigned int red;
  const int bid = blockIdx.x;
  const int tid = threadIdx.x;
  if (bid < 256) {
    const int g = bid * 256 + tid;              // 65536 = 64 * 1024
    const int j = g >> 10, cc = g & 1023;
    float s = bkv[cc];
    for (int i = 0; i < C_; ++i) s += aux[j * C_ + i] * Wkv[i * (2 * C_) + cc];
    kv[g] = s;
    return;
  }
  const bool isW1 = bid < 256 + 1536;
  const int n = isW1 ? (bid - 256) : (bid - 256 - 1536);
  const int ROWS = isW1 ? 512 : 1536;
  const int NC   = isW1 ? 1536 : 512;
  const float* W = isW1 ? W1 : W2;
  if (tid == 0) red = 0;
  __syncthreads();
  float amax = 0.f;
  for (int k = tid; k < ROWS; k += 256)
    amax = fmaxf(amax, fabsf(W[(size_t)k * NC + n]));
#pragma unroll
  for (int off = 1; off < 64; off <<= 1)
    amax = fmaxf(amax, __shfl_xor(amax, off));
  if ((tid & 63) == 0) atomicMax(&red, __float_as_uint(amax));
  __syncthreads();
  if (tid == 0) (isW1 ? w1s : w2s)[n] = fmaxf(__uint_as_float(red), 1e-20f) / 127.0f;
}

// ---------------- precompute stage B: MT, cb, VoT(kappa), W1Q, W2Q(kappa) ----------------

__global__ __launch_bounds__(256) void pre_b(const float* __restrict__ Wq,
                                             const float* __restrict__ bq,
                                             const float* __restrict__ Wo,
                                             const float* __restrict__ kv,
                                             const float* __restrict__ W1,
                                             const float* __restrict__ W2,
                                             const float* __restrict__ w1s,
                                             const float* __restrict__ w2s,
                                             unsigned short* __restrict__ MT,
                                             float* __restrict__ cbias,
                                             unsigned short* __restrict__ VoT,
                                             char* __restrict__ W1Q,
                                             char* __restrict__ W2Q) {
  const int bid = blockIdx.x;
  const int tid = threadIdx.x;
  if (bid < 512) {
    const int col = bid;
    const int h = col >> 6, j = col & 63;
    const float* kvp = kv + j * 1024 + h * 64;
    for (int c = tid; c < C_; c += 256) {
      float s = 0.f;
      for (int d = 0; d < 64; ++d) s += Wq[(size_t)c * C_ + h * 64 + d] * kvp[d];
      MT[(size_t)col * C_ + c] = f2bf(0.125f * s);
    }
    if (tid == 0) {
      float s = 0.f;
      for (int d = 0; d < 64; ++d) s += bq[h * 64 + d] * kvp[d];
      cbias[col] = 0.125f * s;
    }
  } else if (bid < 1024) {
    const int cp = bid - 512;
    for (int k = tid; k < 512; k += 256) {
      const int c = (k >> 7) * 128 + kappa_to_c(k & 127);   // true attention col
      const int h = c >> 6, j = c & 63;
      float s = 0.f;
      for (int d = 0; d < 64; ++d)
        s += kv[j * 1024 + 512 + h * 64 + d] * Wo[(size_t)(h * 64 + d) * C_ + cp];
      VoT[(size_t)cp * 512 + k] = f2bf(s);
    }
  } else if (bid < 4096) {
    const int g = (bid - 1024) * 256 + tid;      // 1536*512
    const int n = g >> 9, k = g & 511;
    W1Q[g] = q8(W1[(size_t)k * I_ + n], 1.0f / w1s[n]);
  } else {
    const int g = (bid - 4096) * 256 + tid;      // 512*1536 : W2Q[n][k] kappa-order
    const int n = g / 1536, k = g - n * 1536;
    const int c = (k >> 7) * 128 + kappa_to_c(k & 127);     // true I-channel
    W2Q[g] = q8(W2[(size_t)c * C_ + n], 1.0f / w2s[n]);
  }
}

// ---------------- x (B,C,T) -> xt bf16 (B*T, C), vectorized stores ----------------

__global__ __launch_bounds__(256) void xt_kernel(const float* __restrict__ x,
                                                 unsigned short* __restrict__ xt) {
  __shared__ float ld[64][65];
  const int tid = threadIdx.x;
  const int t0 = blockIdx.x * 64, c0 = blockIdx.y * 64, b = blockIdx.z;
  for (int idx = tid; idx < 4096; idx += 256) {
    const int r = idx >> 6, cc = idx & 63;
    ld[r][cc] = x[((size_t)(b * C_ + c0 + r)) * T_ + t0 + cc];
  }
  __syncthreads();
#pragma unroll
  for (int s = 0; s < 2; ++s) {
    const int idx = s * 256 + tid;      // 512 = 64 t-rows x 8 col-chunks
    const int tr = idx >> 3, cl8 = (idx & 7) * 8;
    ushort8 o;
#pragma unroll
    for (int qv = 0; qv < 8; ++qv) o[qv] = f2bf(ld[cl8 + qv][tr]);
    *(ushort8*)&xt[((size_t)(b * T_ + t0 + tr)) * C_ + c0 + cl8] = o;
  }
}

// ---------------- GEMM A (m97, BK=64, 8-chunk coalesced swizzled staging) ----------------
template<int N, int K, int NCOL, int EPI>
__global__ __launch_bounds__(256) void gemm_mfma(const unsigned short* __restrict__ A,
                                                 const unsigned short* __restrict__ Bt,
                                                 const float* __restrict__ bias,
                                                 unsigned short* __restrict__ outU,
                                                 const unsigned short* __restrict__ resU,
                                                 float* __restrict__ outF) {
  __shared__ __align__(16) unsigned short shm[EPI == 4 ? 128 * 132 : 128 * 128];
  unsigned short* lA = shm;              // 128 rows x 64 k (8 chunks/row)
  unsigned short* lB = shm + 128 * 64;
  unsigned short* bounce = shm;          // EPI4 only, after K-loop (lA/lB dead)
  const int q = gridDim.x >> 3;
  const int wgid = (blockIdx.x & 7) * q + (blockIdx.x >> 3);
  const int row0 = (wgid / NCOL) * 128;
  const int col0 = (wgid % NCOL) * 128;
  const int tid = threadIdx.x;
  const int w = tid >> 6, lane = tid & 63;
  const int wr = (w >> 1) * 64, wc = (w & 1) * 64;

  const f32x4 zero4 = {0.f, 0.f, 0.f, 0.f};
  f32x4 acc[4][4];
#pragma unroll
  for (int m = 0; m < 4; ++m)
#pragma unroll
    for (int n = 0; n < 4; ++n) acc[m][n] = zero4;

  const int lrow = lane & 15, lg = lane >> 4;

  // hoisted per-thread staging source pointers (one per s-slice)
  const unsigned short* aP[4];
  const unsigned short* bP[4];
#pragma unroll
  for (int s = 0; s < 4; ++s) {
    const int qq = s * 256 + tid;
    const int r = qq >> 3;
    const int kc = swz8_kc(qq, r);
    aP[s] = A + (size_t)(row0 + r) * K + kc * 8;
    bP[s] = Bt + (size_t)(col0 + r) * K + kc * 8;
  }

  for (int k0 = 0; k0 < K; k0 += 64) {
#pragma unroll
    for (int s = 0; s < 4; ++s) {
      const int qq = s * 256 + tid;
      gload_lds16(aP[s] + k0, (char*)lA + qq * 16);
      gload_lds16(bP[s] + k0, (char*)lB + qq * 16);
    }
    __syncthreads();
    short8 av[2][4], bv[2][4];
#pragma unroll
    for (int ks = 0; ks < 2; ++ks) {
      const int ch = ks * 4 + lg;
#pragma unroll
      for (int m = 0; m < 4; ++m) {
        const int ar = wr + m * 16 + lrow;
        av[ks][m] = *(const short8*)&lA[swz8_rd(ar, ch) * 8];
        const int br = wc + m * 16 + lrow;
        bv[ks][m] = *(const short8*)&lB[swz8_rd(br, ch) * 8];
      }
    }
#pragma unroll
    for (int ks = 0; ks < 2; ++ks)
#pragma unroll
      for (int m = 0; m < 4; ++m)
#pragma unroll
        for (int n = 0; n < 4; ++n)
          acc[m][n] = __builtin_amdgcn_mfma_f32_16x16x32_bf16(av[ks][m], bv[ks][n],
                                                              acc[m][n], 0, 0, 0);
    __syncthreads();
  }

  if (EPI == 1) {
    float cbv[4];
#pragma unroll
    for (int n = 0; n < 4; ++n) cbv[n] = bias[col0 + wc + n * 16 + lrow];
    const int kbase = col0 + wc + lrow * 4;
#pragma unroll
    for (int m = 0; m < 4; ++m) {
#pragma unroll
      for (int i = 0; i < 4; ++i) {
        float e0 = acc[m][0][i] + cbv[0];
        float e1 = acc[m][1][i] + cbv[1];
        float e2 = acc[m][2][i] + cbv[2];
        float e3 = acc[m][3][i] + cbv[3];
        float mx = fmaxf(fmaxf(e0, e1), fmaxf(e2, e3));
        mx = fmaxf(mx, __shfl_xor(mx, 1));
        mx = fmaxf(mx, __shfl_xor(mx, 2));
        mx = fmaxf(mx, __shfl_xor(mx, 4));
        mx = fmaxf(mx, __shfl_xor(mx, 8));
        e0 = __expf(e0 - mx); e1 = __expf(e1 - mx);
        e2 = __expf(e2 - mx); e3 = __expf(e3 - mx);
        float s = e0 + e1 + e2 + e3;
        s += __shfl_xor(s, 1);
        s += __shfl_xor(s, 2);
        s += __shfl_xor(s, 4);
        s += __shfl_xor(s, 8);
        const float inv = 1.0f / s;
        us4 pk;
        pk[0] = f2bf(e0 * inv); pk[1] = f2bf(e1 * inv);
        pk[2] = f2bf(e2 * inv); pk[3] = f2bf(e3 * inv);
        *(us4*)&outU[(size_t)(row0 + wr + m * 16 + lg * 4 + i) * N + kbase] = pk;
      }
    }
    return;
  }

  // EPI == 4 : residual epilogue with LDS transpose bounce
#pragma unroll
  for (int m = 0; m < 4; ++m) {
    const int r0 = row0 + wr + m * 16 + (lg << 2);
    const int tl = wr + m * 16 + (lg << 2);
#pragma unroll
    for (int n = 0; n < 4; ++n) {
      const int cl = wc + n * 16 + lrow;
      const int c = col0 + cl;
      const float bb = bias[c];
      us4 pk;
#pragma unroll
      for (int i = 0; i < 4; ++i)
        pk[i] = f2bf(bf2f(resU[(size_t)(r0 + i) * 512 + c]) + acc[m][n][i] + bb);
      *(us4*)&bounce[cl * 132 + tl] = pk;
    }
  }
  __syncthreads();
  const int bidx = row0 >> 12;
  const int t0 = row0 & 4095;
#pragma unroll
  for (int j = 0; j < 8; ++j) {
    const int cl = j * 16 + w * 4 + (lane >> 4);
    const int t = (lane & 15) * 8;
    const ushort8 v = *(const ushort8*)&bounce[cl * 132 + t];
    *(ushort8*)&outU[((size_t)(bidx * C_ + col0 + cl)) * T_ + t0 + t] = v;
  }
}

// ---------------- GEMM B: int8, 8 waves, 128x256 tile, BK=64, 3-buf, coalesced staging ------
template<int N, int K, int NCOL, int EPI>
__global__ __launch_bounds__(512, 4) void gemm8w(const char* __restrict__ A,
                                                 const char* __restrict__ Bt,
                                                 const float* __restrict__ rowS,
                                                 const float* __restrict__ colS,
                                                 const float* __restrict__ bias,
                                                 char* __restrict__ outQ,
                                                 const unsigned short* __restrict__ resU,
                                                 float* __restrict__ outF) {
  __shared__ __align__(16) char lds[73728];
  const int tid = threadIdx.x;
  const int w = tid >> 6, lane = tid & 63;
  const int wm = w >> 2, wn = w & 3;            // 2x4 wave grid
  const int lrow = lane & 15, lg = lane >> 4;
  const int q8g = gridDim.x >> 3;
  const int wgid = (blockIdx.x & 7) * q8g + (blockIdx.x >> 3);
  const int row0 = (wgid / NCOL) * 128;
  const int col0 = (wgid % NCOL) * 128 * 2;     // BN=256

  // hoisted per-thread staging source pointers
  const char* aP0;
  const char* bP0;
  const char* bP1;
  {
    const int rA = tid >> 2, kcA = swz_kc(tid, rA);
    aP0 = A + (size_t)(row0 + rA) * K + kcA * 16;
    const int r0b = tid >> 2, kc0 = swz_kc(tid, r0b);
    bP0 = Bt + (size_t)(col0 + r0b) * K + kc0 * 16;
    const int q1 = 512 + tid;
    const int r1b = q1 >> 2, kc1 = swz_kc(q1, r1b);
    bP1 = Bt + (size_t)(col0 + r1b) * K + kc1 * 16;
  }
  auto stageA = [&](int kt, int b) {
    gload_lds16(aP0 + kt * 64, lds + b * 8192 + tid * 16);
  };
  auto stageB = [&](int kt, int b) {
    gload_lds16(bP0 + kt * 64, lds + 24576 + b * 16384 + tid * 16);
    gload_lds16(bP1 + kt * 64, lds + 24576 + b * 16384 + (512 + tid) * 16);
  };

  const i32x4 zero4 = {0, 0, 0, 0};
  i32x4 acc[4][4];
#pragma unroll
  for (int m = 0; m < 4; ++m)
#pragma unroll
    for (int n = 0; n < 4; ++n) acc[m][n] = zero4;

  const int KT = K / 64;     // G3: 8, G4: 24

  stageA(0, 0); stageB(0, 0);
  stageA(1, 1); stageB(1, 1);
  asm volatile("s_waitcnt vmcnt(3)" ::: "memory");
  __builtin_amdgcn_s_barrier();

  int cur = 0;
  for (int t = 0; t < KT; ++t) {
    if (t + 2 < KT) {
      const int nb = (cur + 2 >= 3) ? cur - 1 : cur + 2;
      stageA(t + 2, nb); stageB(t + 2, nb);
    }
    const char* ab = lds + cur * 8192;
    const char* bb = lds + 24576 + cur * 16384;
    i32x4 av[4], bv[4];
#pragma unroll
    for (int mf = 0; mf < 4; ++mf) {
      const int ar = wm * 64 + mf * 16 + lrow;
      av[mf] = *(const i32x4*)(ab + (size_t)swz_rd(ar, lg) * 16);
    }
#pragma unroll
    for (int nf = 0; nf < 4; ++nf) {
      const int br = wn * 64 + nf * 16 + lrow;
      bv[nf] = *(const i32x4*)(bb + (size_t)swz_rd(br, lg) * 16);
    }
    __builtin_amdgcn_s_setprio(1);
#pragma unroll
    for (int mf = 0; mf < 4; ++mf)
#pragma unroll
      for (int nf = 0; nf < 4; ++nf)
        acc[mf][nf] = __builtin_amdgcn_mfma_i32_16x16x64_i8(av[mf], bv[nf],
                                                            acc[mf][nf], 0, 0, 0);
    __builtin_amdgcn_s_setprio(0);
    if (t + 2 < KT) { asm volatile("s_waitcnt vmcnt(3)" ::: "memory"); }
    else            { asm volatile("s_waitcnt vmcnt(0)" ::: "memory"); }
    __builtin_amdgcn_s_barrier();
    cur = (cur == 2) ? 0 : cur + 1;
  }

  if (EPI == 3) {
    const int kbase = col0 + (wn >> 1) * 128 + (wn & 1) * 64 + lrow * 4;
#pragma unroll
    for (int mf = 0; mf < 4; ++mf) {
      const int r0 = row0 + wm * 64 + mf * 16 + lg * 4;
      float rs4[4];
#pragma unroll
      for (int i = 0; i < 4; ++i) rs4[i] = rowS[r0 + i];
      float dsv[4], bbv[4];
#pragma unroll
      for (int nf = 0; nf < 4; ++nf) {
        const int c = col0 + wn * 64 + nf * 16 + lrow;
        dsv[nf] = colS[c];
        bbv[nf] = bias[c];
      }
#pragma unroll
      for (int i = 0; i < 4; ++i) {
        unsigned int pk = 0;
#pragma unroll
        for (int nf = 0; nf < 4; ++nf) {
          const float v = fmaf((float)acc[mf][nf][i], rs4[i] * dsv[nf], bbv[nf]);
          const float g = gelu_f(v);
          // q8i clamps to +-127 == +-3/H1S: identical to explicit +-3 clamp
          const unsigned int b = (unsigned int)(unsigned char)(char)q8i(g, IH1S);
          pk |= b << (8 * nf);
        }
        *(unsigned int*)&outQ[(size_t)(r0 + i) * N + kbase] = pk;
      }
    }
    return;
  }

  // EPI == 5 : 2-pass LDS bounce (128c x 128t f32, stride 132) -> coalesced stores
  float* fb = (float*)lds;
  const int bidx = row0 >> 12;
  const int t0 = row0 & 4095;
#pragma unroll
  for (int p = 0; p < 2; ++p) {
    if ((wn >> 1) == p) {
#pragma unroll
      for (int mf = 0; mf < 4; ++mf) {
        const int tl = wm * 64 + mf * 16 + lg * 4;
#pragma unroll
        for (int nf = 0; nf < 4; ++nf) {
          const int cl = (wn & 1) * 64 + nf * 16 + lrow;
          const int c = col0 + p * 128 + cl;
          const float ds = H1S * colS[c];
          const float bb = bias[c];
          f32x4 v;
#pragma unroll
          for (int i = 0; i < 4; ++i) v[i] = fmaf((float)acc[mf][nf][i], ds, bb);
          *(f32x4*)&fb[cl * 132 + tl] = v;
        }
      }
    }
    __syncthreads();
#pragma unroll
    for (int j = 0; j < 8; ++j) {
      const int cl = j * 16 + w * 2 + (lane >> 5);
      const int t = (lane & 31) * 4;
      const f32x4 v = *(const f32x4*)&fb[cl * 132 + t];
      const size_t addr = ((size_t)(bidx * C_ + col0 + p * 128 + cl)) * T_ + t0 + t;
      const us4 rv = *(const us4*)&resU[addr];
      f32x4 o;
#pragma unroll
      for (int i = 0; i < 4; ++i) o[i] = v[i] + bf2f(rv[i]);
      *(f32x4*)&outF[addr] = o;
    }
    __syncthreads();
  }
}

// ---------------- fused conv1d(k=7,p=3) + AdaLayerNorm -> int8 yln + per-token scale --------

__global__ __launch_bounds__(256) void convq_kernel(
    const unsigned short* __restrict__ rs,
    const float* __restrict__ dww,
    const float* __restrict__ dwb,
    const int* __restrict__ ids,
    const float* __restrict__ sce,
    const float* __restrict__ she,
    char* __restrict__ ylnq,
    float* __restrict__ yscale) {
  __shared__ unsigned short rbuf[512 * 28];   // [c][16t window + pad]
  __shared__ float cbuf[8 * 520];
  const int tid = threadIdx.x;
  const int t0 = blockIdx.x * 8;
  const int b = blockIdx.y;
  const int w0 = t0 - 4;                      // window [w0, w0+16)
#pragma unroll
  for (int s = 0; s < 8; ++s) {
    const int f = s * 256 + tid;
    const int c = f >> 2, j = f & 3;
    const int t = w0 + j * 4;
    us4 v = {0, 0, 0, 0};
    if (t >= 0 && t + 3 < T_) {
      v = *(const us4*)&rs[((size_t)(b * C_ + c)) * T_ + t];
    } else {
#pragma unroll
      for (int e = 0; e < 4; ++e)
        if (t + e >= 0 && t + e < T_) v[e] = rs[((size_t)(b * C_ + c)) * T_ + t + e];
    }
    *(us4*)&rbuf[c * 28 + j * 4] = v;
  }
  __syncthreads();
#pragma unroll
  for (int cc = 0; cc < 2; ++cc) {
    const int c = cc * 256 + tid;
    float f[15];
#pragma unroll
    for (int i = 0; i < 15; ++i) f[i] = bf2f(rbuf[c * 28 + i]);
    float wk[7];
#pragma unroll
    for (int k = 0; k < 7; ++k) wk[k] = dww[c * 7 + k];
    const float bb = dwb[c];
#pragma unroll
    for (int tt = 0; tt < 8; ++tt) {
      float s = bb;
#pragma unroll
      for (int k = 0; k < 7; ++k) s += f[tt + 1 + k] * wk[k];
      cbuf[tt * 520 + c] = s;
    }
  }
  __syncthreads();
  const int lane = tid & 63, w = tid >> 6;
  const int id = ids[b];
#pragma unroll
  for (int tt = 0; tt < 2; ++tt) {
    const int t = w * 2 + tt;
    const f32x4 v0 = *(const f32x4*)&cbuf[t * 520 + lane * 8];
    const f32x4 v1 = *(const f32x4*)&cbuf[t * 520 + lane * 8 + 4];
    float s = 0.f, sq = 0.f;
#pragma unroll
    for (int i = 0; i < 4; ++i) { s += v0[i]; sq += v0[i] * v0[i]; }
#pragma unroll
    for (int i = 0; i < 4; ++i) { s += v1[i]; sq += v1[i] * v1[i]; }
#pragma unroll
    for (int off = 1; off < 64; off <<= 1) {
      s += __shfl_xor(s, off);
      sq += __shfl_xor(sq, off);
    }
    const float mean = s * (1.0f / 512.0f);
    const float var = sq * (1.0f / 512.0f) - mean * mean;
    const float rstd = rsqrtf(var + 1e-6f);
    const f32x4 sc0 = *(const f32x4*)&sce[id * C_ + lane * 8];
    const f32x4 sc1 = *(const f32x4*)&sce[id * C_ + lane * 8 + 4];
    const f32x4 sh0 = *(const f32x4*)&she[id * C_ + lane * 8];
    const f32x4 sh1 = *(const f32x4*)&she[id * C_ + lane * 8 + 4];
    float y[8];
    float amax = 0.f;
#pragma unroll
    for (int i = 0; i < 4; ++i) {
      y[i]     = (v0[i] - mean) * rstd * sc0[i] + sh0[i];
      y[4 + i] = (v1[i] - mean) * rstd * sc1[i] + sh1[i];
    }
#pragma unroll
    for (int i = 0; i < 8; ++i) amax = fmaxf(amax, fabsf(y[i]));
#pragma unroll
    for (int off = 1; off < 64; off <<= 1) amax = fmaxf(amax, __shfl_xor(amax, off));
    amax = fmaxf(amax, 1e-20f);
    const float inv = 127.0f / amax;
    const int tg = b * T_ + t0 + t;
    char8v o;
#pragma unroll
    for (int i = 0; i < 8; ++i) o[i] = q8(y[i], inv);
    *(char8v*)&ylnq[(size_t)tg * C_ + lane * 8] = o;
    if (lane == 0) yscale[tg] = amax * (1.0f / 127.0f);
  }
}

// ---------------- launch ----------------

extern "C" void kernel_launch(void* const* d_in, const int* in_sizes, int n_in,
                              void* d_out, int out_size, void* d_ws, size_t ws_size,
                              hipStream_t stream) {
  const float* x   = (const float*)d_in[0];
  const int*   ids = (const int*)d_in[1];
  const float* Wq  = (const float*)d_in[2];
  const float* bq  = (const float*)d_in[3];
  const float* Wkv = (const float*)d_in[4];
  const float* bkv = (const float*)d_in[5];
  const float* Wo  = (const float*)d_in[6];
  const float* bo  = (const float*)d_in[7];
  const float* dww = (const float*)d_in[8];
  const float* dwb = (const float*)d_in[9];
  const float* sce = (const float*)d_in[10];
  const float* she = (const float*)d_in[11];
  const float* W1  = (const float*)d_in[12];
  const float* b1  = (const float*)d_in[13];
  const float* W2  = (const float*)d_in[14];
  const float* b2  = (const float*)d_in[15];
  const float* aux = (const float*)d_in[16];
  float* out = (float*)d_out;

  char* ws = (char*)d_ws;
  unsigned short* xt   = (unsigned short*)(ws + 0);              // 64 MB
  unsigned short* P    = (unsigned short*)(ws + (64u  << 20));   // 64 MB
  char*           ylnq = (char*)(ws + (64u << 20));              // 32 MB (overlays P; P dead)
  float*          ysc  = (float*)(ws + (100u << 20));            // 256 KB
  unsigned short* rs   = (unsigned short*)(ws + (128u << 20));   // 64 MB (bf16)
  char*           H1Q  = (char*)(ws + (192u << 20));             // 96 MB (i8)
  char* sm = ws + (384u << 20);
  float*          kv   = (float*)(sm);                           // 256 KB
  float*          cb   = (float*)(sm + 262144);                  // 2 KB
  unsigned short* MT   = (unsigned short*)(sm + 264192);         // 512 KB
  unsigned short* VoT  = (unsigned short*)(sm + 788480);         // 512 KB
  char*           W1Q  = (char*)(sm + 1312768);                  // 768 KB
  char*           W2Q  = (char*)(sm + 2099200);                  // 768 KB
  float*          w1s  = (float*)(sm + 2885632);                 // 6 KB
  float*          w2s  = (float*)(sm + 2891776);                 // 2 KB

  pre_a<<<dim3(2304), dim3(256), 0, stream>>>(aux, Wkv, bkv, W1, W2, kv, w1s, w2s);
  pre_b<<<dim3(7168), dim3(256), 0, stream>>>(Wq, bq, Wo, kv, W1, W2, w1s, w2s,
                                              MT, cb, VoT, W1Q, W2Q);
  xt_kernel<<<dim3(64, 8, 16), dim3(256), 0, stream>>>(x, xt);

  // attention as two BK=64 m97-structure GEMMs with packed/bounced epilogues
  gemm_mfma<512, 512, 4, 1><<<dim3(2048), dim3(256), 0, stream>>>(
      xt, MT, cb, P, nullptr, nullptr);
  gemm_mfma<512, 512, 4, 4><<<dim3(2048), dim3(256), 0, stream>>>(
      P, VoT, bo, rs, xt, nullptr);
  convq_kernel<<<dim3(512, 16), dim3(256), 0, stream>>>(rs, dww, dwb, ids, sce, she,
                                                        ylnq, ysc);
  // MLP as two int8 8-wave GEMMs, coalesced staging + swizzled LDS chunks
  gemm8w<1536, 512, 6, 3><<<dim3(3072), dim3(512), 0, stream>>>(
      ylnq, W1Q, ysc, w1s, b1, H1Q, nullptr, nullptr);
  gemm8w<512, 1536, 2, 5><<<dim3(1024), dim3(512), 0, stream>>>(
      H1Q, W2Q, nullptr, w2s, b2, nullptr, rs, out);
}

// Round 21
// 523.477 us; speedup vs baseline: 1.3982x; 1.0065x over previous
//
#include <hip/hip_runtime.h>
#include <hip/hip_bf16.h>
#include <math.h>

#define B_ 16
#define C_ 512
#define T_ 4096
#define I_ 1536

typedef short short8 __attribute__((ext_vector_type(8)));
typedef unsigned short ushort8 __attribute__((ext_vector_type(8)));
typedef unsigned short us4 __attribute__((ext_vector_type(4)));
typedef float f32x4 __attribute__((ext_vector_type(4)));
typedef int i32x4 __attribute__((ext_vector_type(4)));
typedef char char8v __attribute__((ext_vector_type(8)));

static __device__ __forceinline__ unsigned short f2bf(float f) {
  union { float f; unsigned int u; } v; v.f = f;
  unsigned int r = v.u + 0x7fffu + ((v.u >> 16) & 1u);
  return (unsigned short)(r >> 16);
}
static __device__ __forceinline__ float bf2f(unsigned short h) {
  union { unsigned int u; float f; } v; v.u = ((unsigned int)h) << 16;
  return v.f;
}

static __device__ __forceinline__ float fast_rcp(float x) {
  float r; asm("v_rcp_f32 %0, %1" : "=v"(r) : "v"(x)); return r;
}

// tanh-form GELU. |err vs erf| <= ~3e-3/elem, diluted by @W2.
static __device__ __forceinline__ float gelu_f(float v) {
  const float v2 = v * v;
  const float w = v * (0.7978845608f + 0.0356774081f * v2);
  const float a = fminf(w * 2.8853900818f, 126.0f);
  const float u = exp2f(a);
  return v * u * fast_rcp(u + 1.0f);
}

static __device__ __forceinline__ int q8i(float v, float inv) {
  int q = __float2int_rn(v * inv);
  q = q > 127 ? 127 : (q < -127 ? -127 : q);
  return q;
}
static __device__ __forceinline__ char q8(float v, float inv) {
  return (char)q8i(v, inv);
}

__device__ __forceinline__ void gload_lds16(const void* g, void* l) {
  __builtin_amdgcn_global_load_lds((const __attribute__((address_space(1))) void*)g,
                                   (__attribute__((address_space(3))) void*)l, 16, 0, 0);
}

#define H1S   (3.0f / 127.0f)
#define IH1S  (127.0f / 3.0f)

// kappa-permutation within each 128-col block
static __device__ __forceinline__ int kappa_to_c(int k128) {
  const int wcbit = k128 >> 6, lrow = (k128 & 63) >> 2, n = k128 & 3;
  return wcbit * 64 + n * 16 + lrow;
}
static __device__ __forceinline__ int c_to_kappa(int c128) {
  return (c128 >> 6) * 64 + (c128 & 15) * 4 + ((c128 & 63) >> 4);
}

// 4-chunk staging swizzle (64B rows)
static __device__ __forceinline__ int swz_kc(int q, int row) {
  return (q & 3) ^ ((row >> 1) & 3);
}
static __device__ __forceinline__ int swz_rd(int row, int lg) {
  return row * 4 + (lg ^ ((row >> 1) & 3));
}
// 8-chunk staging swizzle (128B rows, bf16 BK=64)
static __device__ __forceinline__ int swz8_kc(int q, int row) {
  return (q & 7) ^ ((row >> 1) & 7);
}
static __device__ __forceinline__ int swz8_rd(int row, int chunk) {
  return row * 8 + (chunk ^ ((row >> 1) & 7));
}

// ---------------- precompute stage A: kv + weight scales ----------------

__global__ __launch_bounds__(256) void pre_a(const float* __restrict__ aux,
                                             const float* __restrict__ Wkv,
                                             const float* __restrict__ bkv,
                                             const float* __restrict__ W1,
                                             const float* __restrict__ W2,
                                             float* __restrict__ kv,
                                             float* __restrict__ w1s,
                                             float* __restrict__ w2s) {
  __shared__ unsigned int red;
  const int bid = blockIdx.x;
  const int tid = threadIdx.x;
  if (bid < 256) {
    const int g = bid * 256 + tid;              // 65536 = 64 * 1024
    const int j = g >> 10, cc = g & 1023;
    float s = bkv[cc];
    for (int i = 0; i < C_; ++i) s += aux[j * C_ + i] * Wkv[i * (2 * C_) + cc];
    kv[g] = s;
    return;
  }
  const bool isW1 = bid < 256 + 1536;
  const int n = isW1 ? (bid - 256) : (bid - 256 - 1536);
  const int ROWS = isW1 ? 512 : 1536;
  const int NC   = isW1 ? 1536 : 512;
  const float* W = isW1 ? W1 : W2;
  if (tid == 0) red = 0;
  __syncthreads();
  float amax = 0.f;
  for (int k = tid; k < ROWS; k += 256)
    amax = fmaxf(amax, fabsf(W[(size_t)k * NC + n]));
#pragma unroll
  for (int off = 1; off < 64; off <<= 1)
    amax = fmaxf(amax, __shfl_xor(amax, off));
  if ((tid & 63) == 0) atomicMax(&red, __float_as_uint(amax));
  __syncthreads();
  if (tid == 0) (isW1 ? w1s : w2s)[n] = fmaxf(__uint_as_float(red), 1e-20f) / 127.0f;
}

// ---------------- precompute stage B: MT, cb, VoT(kappa) ----------------

__global__ __launch_bounds__(256) void pre_b(const float* __restrict__ Wq,
                                             const float* __restrict__ bq,
                                             const float* __restrict__ Wo,
                                             const float* __restrict__ kv,
                                             unsigned short* __restrict__ MT,
                                             float* __restrict__ cbias,
                                             unsigned short* __restrict__ VoT) {
  const int bid = blockIdx.x;
  const int tid = threadIdx.x;
  if (bid < 512) {
    const int col = bid;
    const int h = col >> 6, j = col & 63;
    const float* kvp = kv + j * 1024 + h * 64;
    for (int c = tid; c < C_; c += 256) {
      float s = 0.f;
      for (int d = 0; d < 64; ++d) s += Wq[(size_t)c * C_ + h * 64 + d] * kvp[d];
      MT[(size_t)col * C_ + c] = f2bf(0.125f * s);
    }
    if (tid == 0) {
      float s = 0.f;
      for (int d = 0; d < 64; ++d) s += bq[h * 64 + d] * kvp[d];
      cbias[col] = 0.125f * s;
    }
  } else {
    const int cp = bid - 512;
    for (int k = tid; k < 512; k += 256) {
      const int c = (k >> 7) * 128 + kappa_to_c(k & 127);   // true attention col
      const int h = c >> 6, j = c & 63;
      float s = 0.f;
      for (int d = 0; d < 64; ++d)
        s += kv[j * 1024 + 512 + h * 64 + d] * Wo[(size_t)(h * 64 + d) * C_ + cp];
      VoT[(size_t)cp * 512 + k] = f2bf(s);
    }
  }
}

// ---------------- precompute stage W: coalesced transpose-quantize of W1/W2 ----------------
// bid<96: W1 tiles (64n x 128k). bid 96..191: W2 tiles (kappa applied at LDS write).
// Pass1: lanes<->consecutive n -> coalesced f32 reads; byte writes tile[n*132+perm(r)]
// (stride 132 = 33 words -> 32 distinct banks over 32 lanes, 2-way over 64 = free).
// Pass2: 4x ds_read_b32 (4-aligned) -> one coalesced 16B global store per thread.

__global__ __launch_bounds__(256) void pre_w(const float* __restrict__ W1,
                                             const float* __restrict__ W2,
                                             const float* __restrict__ w1s,
                                             const float* __restrict__ w2s,
                                             char* __restrict__ W1Q,
                                             char* __restrict__ W2Q) {
  __shared__ char tile[64 * 132];
  __shared__ float invs[64];
  const int bid = blockIdx.x, tid = threadIdx.x;
  const bool isW1 = bid < 96;
  int n0, k0, NC;
  if (isW1) { n0 = (bid >> 2) * 64; k0 = (bid & 3) * 128; NC = 1536; }
  else      { const int t = bid - 96; n0 = (t / 12) * 64; k0 = (t % 12) * 128; NC = 512; }
  const float* W = isW1 ? W1 : W2;
  if (tid < 64) invs[tid] = 1.0f / (isW1 ? w1s[n0 + tid] : w2s[n0 + tid]);
  __syncthreads();
  const int n = tid & 63;
  const float inv = invs[n];
#pragma unroll
  for (int s = 0; s < 32; ++s) {
    const int f = s * 256 + tid;
    const int r = f >> 6;                       // 0..127
    const int pr = isW1 ? r : c_to_kappa(r);    // kappa k-permutation for W2
    tile[n * 132 + pr] = q8(W[(size_t)(k0 + r) * NC + n0 + n], inv);
  }
  __syncthreads();
#pragma unroll
  for (int s = 0; s < 2; ++s) {
    const int idx = s * 256 + tid;              // 512 = 64n x 8kc
    const int nn = idx >> 3, kc = idx & 7;
    i32x4 pk;
#pragma unroll
    for (int j = 0; j < 4; ++j)
      pk[j] = *(const int*)&tile[nn * 132 + kc * 16 + j * 4];
    if (isW1) *(i32x4*)&W1Q[(size_t)(n0 + nn) * 512 + k0 + kc * 16] = pk;
    else      *(i32x4*)&W2Q[(size_t)(n0 + nn) * 1536 + k0 + kc * 16] = pk;
  }
}

// ---------------- x (B,C,T) -> xt bf16 (B*T, C), vectorized stores ----------------

__global__ __launch_bounds__(256) void xt_kernel(const float* __restrict__ x,
                                                 unsigned short* __restrict__ xt) {
  __shared__ float ld[64][65];
  const int tid = threadIdx.x;
  const int t0 = blockIdx.x * 64, c0 = blockIdx.y * 64, b = blockIdx.z;
  for (int idx = tid; idx < 4096; idx += 256) {
    const int r = idx >> 6, cc = idx & 63;
    ld[r][cc] = x[((size_t)(b * C_ + c0 + r)) * T_ + t0 + cc];
  }
  __syncthreads();
#pragma unroll
  for (int s = 0; s < 2; ++s) {
    const int idx = s * 256 + tid;      // 512 = 64 t-rows x 8 col-chunks
    const int tr = idx >> 3, cl8 = (idx & 7) * 8;
    ushort8 o;
#pragma unroll
    for (int qv = 0; qv < 8; ++qv) o[qv] = f2bf(ld[cl8 + qv][tr]);
    *(ushort8*)&xt[((size_t)(b * T_ + t0 + tr)) * C_ + c0 + cl8] = o;
  }
}

// ---------------- GEMM A (m97, BK=64, 8-chunk coalesced swizzled staging) ----------------
template<int N, int K, int NCOL, int EPI>
__global__ __launch_bounds__(256) void gemm_mfma(const unsigned short* __restrict__ A,
                                                 const unsigned short* __restrict__ Bt,
                                                 const float* __restrict__ bias,
                                                 unsigned short* __restrict__ outU,
                                                 const unsigned short* __restrict__ resU,
                                                 float* __restrict__ outF) {
  __shared__ __align__(16) unsigned short shm[EPI == 4 ? 128 * 132 : 128 * 128];
  unsigned short* lA = shm;              // 128 rows x 64 k (8 chunks/row)
  unsigned short* lB = shm + 128 * 64;
  unsigned short* bounce = shm;          // EPI4 only, after K-loop (lA/lB dead)
  const int q = gridDim.x >> 3;
  const int wgid = (blockIdx.x & 7) * q + (blockIdx.x >> 3);
  const int row0 = (wgid / NCOL) * 128;
  const int col0 = (wgid % NCOL) * 128;
  const int tid = threadIdx.x;
  const int w = tid >> 6, lane = tid & 63;
  const int wr = (w >> 1) * 64, wc = (w & 1) * 64;

  const f32x4 zero4 = {0.f, 0.f, 0.f, 0.f};
  f32x4 acc[4][4];
#pragma unroll
  for (int m = 0; m < 4; ++m)
#pragma unroll
    for (int n = 0; n < 4; ++n) acc[m][n] = zero4;

  const int lrow = lane & 15, lg = lane >> 4;

  // hoisted per-thread staging source pointers (one per s-slice)
  const unsigned short* aP[4];
  const unsigned short* bP[4];
#pragma unroll
  for (int s = 0; s < 4; ++s) {
    const int qq = s * 256 + tid;
    const int r = qq >> 3;
    const int kc = swz8_kc(qq, r);
    aP[s] = A + (size_t)(row0 + r) * K + kc * 8;
    bP[s] = Bt + (size_t)(col0 + r) * K + kc * 8;
  }

  for (int k0 = 0; k0 < K; k0 += 64) {
#pragma unroll
    for (int s = 0; s < 4; ++s) {
      const int qq = s * 256 + tid;
      gload_lds16(aP[s] + k0, (char*)lA + qq * 16);
      gload_lds16(bP[s] + k0, (char*)lB + qq * 16);
    }
    __syncthreads();
    short8 av[2][4], bv[2][4];
#pragma unroll
    for (int ks = 0; ks < 2; ++ks) {
      const int ch = ks * 4 + lg;
#pragma unroll
      for (int m = 0; m < 4; ++m) {
        const int ar = wr + m * 16 + lrow;
        av[ks][m] = *(const short8*)&lA[swz8_rd(ar, ch) * 8];
        const int br = wc + m * 16 + lrow;
        bv[ks][m] = *(const short8*)&lB[swz8_rd(br, ch) * 8];
      }
    }
#pragma unroll
    for (int ks = 0; ks < 2; ++ks)
#pragma unroll
      for (int m = 0; m < 4; ++m)
#pragma unroll
        for (int n = 0; n < 4; ++n)
          acc[m][n] = __builtin_amdgcn_mfma_f32_16x16x32_bf16(av[ks][m], bv[ks][n],
                                                              acc[m][n], 0, 0, 0);
    __syncthreads();
  }

  if (EPI == 1) {
    float cbv[4];
#pragma unroll
    for (int n = 0; n < 4; ++n) cbv[n] = bias[col0 + wc + n * 16 + lrow];
    const int kbase = col0 + wc + lrow * 4;
#pragma unroll
    for (int m = 0; m < 4; ++m) {
#pragma unroll
      for (int i = 0; i < 4; ++i) {
        float e0 = acc[m][0][i] + cbv[0];
        float e1 = acc[m][1][i] + cbv[1];
        float e2 = acc[m][2][i] + cbv[2];
        float e3 = acc[m][3][i] + cbv[3];
        float mx = fmaxf(fmaxf(e0, e1), fmaxf(e2, e3));
        mx = fmaxf(mx, __shfl_xor(mx, 1));
        mx = fmaxf(mx, __shfl_xor(mx, 2));
        mx = fmaxf(mx, __shfl_xor(mx, 4));
        mx = fmaxf(mx, __shfl_xor(mx, 8));
        e0 = __expf(e0 - mx); e1 = __expf(e1 - mx);
        e2 = __expf(e2 - mx); e3 = __expf(e3 - mx);
        float s = e0 + e1 + e2 + e3;
        s += __shfl_xor(s, 1);
        s += __shfl_xor(s, 2);
        s += __shfl_xor(s, 4);
        s += __shfl_xor(s, 8);
        const float inv = 1.0f / s;
        us4 pk;
        pk[0] = f2bf(e0 * inv); pk[1] = f2bf(e1 * inv);
        pk[2] = f2bf(e2 * inv); pk[3] = f2bf(e3 * inv);
        *(us4*)&outU[(size_t)(row0 + wr + m * 16 + lg * 4 + i) * N + kbase] = pk;
      }
    }
    return;
  }

  // EPI == 4 : residual epilogue with LDS transpose bounce
#pragma unroll
  for (int m = 0; m < 4; ++m) {
    const int r0 = row0 + wr + m * 16 + (lg << 2);
    const int tl = wr + m * 16 + (lg << 2);
#pragma unroll
    for (int n = 0; n < 4; ++n) {
      const int cl = wc + n * 16 + lrow;
      const int c = col0 + cl;
      const float bb = bias[c];
      us4 pk;
#pragma unroll
      for (int i = 0; i < 4; ++i)
        pk[i] = f2bf(bf2f(resU[(size_t)(r0 + i) * 512 + c]) + acc[m][n][i] + bb);
      *(us4*)&bounce[cl * 132 + tl] = pk;
    }
  }
  __syncthreads();
  const int bidx = row0 >> 12;
  const int t0 = row0 & 4095;
#pragma unroll
  for (int j = 0; j < 8; ++j) {
    const int cl = j * 16 + w * 4 + (lane >> 4);
    const int t = (lane & 15) * 8;
    const ushort8 v = *(const ushort8*)&bounce[cl * 132 + t];
    *(ushort8*)&outU[((size_t)(bidx * C_ + col0 + cl)) * T_ + t0 + t] = v;
  }
}

// ---------------- GEMM B: int8, 8 waves, 128x256 tile, BK=64, 3-buf, coalesced staging ------
template<int N, int K, int NCOL, int EPI>
__global__ __launch_bounds__(512, 4) void gemm8w(const char* __restrict__ A,
                                                 const char* __restrict__ Bt,
                                                 const float* __restrict__ rowS,
                                                 const float* __restrict__ colS,
                                                 const float* __restrict__ bias,
                                                 char* __restrict__ outQ,
                                                 const unsigned short* __restrict__ resU,
                                                 float* __restrict__ outF) {
  __shared__ __align__(16) char lds[73728];
  const int tid = threadIdx.x;
  const int w = tid >> 6, lane = tid & 63;
  const int wm = w >> 2, wn = w & 3;            // 2x4 wave grid
  const int lrow = lane & 15, lg = lane >> 4;
  const int q8g = gridDim.x >> 3;
  const int wgid = (blockIdx.x & 7) * q8g + (blockIdx.x >> 3);
  const int row0 = (wgid / NCOL) * 128;
  const int col0 = (wgid % NCOL) * 128 * 2;     // BN=256

  // hoisted per-thread staging source pointers
  const char* aP0;
  const char* bP0;
  const char* bP1;
  {
    const int rA = tid >> 2, kcA = swz_kc(tid, rA);
    aP0 = A + (size_t)(row0 + rA) * K + kcA * 16;
    bP0 = Bt + (size_t)(col0 + rA) * K + kcA * 16;
    const int q1 = 512 + tid;
    const int r1b = q1 >> 2, kc1 = swz_kc(q1, r1b);
    bP1 = Bt + (size_t)(col0 + r1b) * K + kc1 * 16;
  }
  auto stageA = [&](int kt, int b) {
    gload_lds16(aP0 + kt * 64, lds + b * 8192 + tid * 16);
  };
  auto stageB = [&](int kt, int b) {
    gload_lds16(bP0 + kt * 64, lds + 24576 + b * 16384 + tid * 16);
    gload_lds16(bP1 + kt * 64, lds + 24576 + b * 16384 + (512 + tid) * 16);
  };

  const i32x4 zero4 = {0, 0, 0, 0};
  i32x4 acc[4][4];
#pragma unroll
  for (int m = 0; m < 4; ++m)
#pragma unroll
    for (int n = 0; n < 4; ++n) acc[m][n] = zero4;

  const int KT = K / 64;     // G3: 8, G4: 24

  stageA(0, 0); stageB(0, 0);
  stageA(1, 1); stageB(1, 1);
  asm volatile("s_waitcnt vmcnt(3)" ::: "memory");
  __builtin_amdgcn_s_barrier();

  int cur = 0;
  for (int t = 0; t < KT; ++t) {
    if (t + 2 < KT) {
      const int nb = (cur + 2 >= 3) ? cur - 1 : cur + 2;
      stageA(t + 2, nb); stageB(t + 2, nb);
    }
    const char* ab = lds + cur * 8192;
    const char* bb = lds + 24576 + cur * 16384;
    i32x4 av[4], bv[4];
#pragma unroll
    for (int mf = 0; mf < 4; ++mf) {
      const int ar = wm * 64 + mf * 16 + lrow;
      av[mf] = *(const i32x4*)(ab + (size_t)swz_rd(ar, lg) * 16);
    }
#pragma unroll
    for (int nf = 0; nf < 4; ++nf) {
      const int br = wn * 64 + nf * 16 + lrow;
      bv[nf] = *(const i32x4*)(bb + (size_t)swz_rd(br, lg) * 16);
    }
    __builtin_amdgcn_s_setprio(1);
#pragma unroll
    for (int mf = 0; mf < 4; ++mf)
#pragma unroll
      for (int nf = 0; nf < 4; ++nf)
        acc[mf][nf] = __builtin_amdgcn_mfma_i32_16x16x64_i8(av[mf], bv[nf],
                                                            acc[mf][nf], 0, 0, 0);
    __builtin_amdgcn_s_setprio(0);
    if (t + 2 < KT) { asm volatile("s_waitcnt vmcnt(3)" ::: "memory"); }
    else            { asm volatile("s_waitcnt vmcnt(0)" ::: "memory"); }
    __builtin_amdgcn_s_barrier();
    cur = (cur == 2) ? 0 : cur + 1;
  }

  if (EPI == 3) {
    const int kbase = col0 + (wn >> 1) * 128 + (wn & 1) * 64 + lrow * 4;
#pragma unroll
    for (int mf = 0; mf < 4; ++mf) {
      const int r0 = row0 + wm * 64 + mf * 16 + lg * 4;
      float rs4[4];
#pragma unroll
      for (int i = 0; i < 4; ++i) rs4[i] = rowS[r0 + i];
      float dsv[4], bbv[4];
#pragma unroll
      for (int nf = 0; nf < 4; ++nf) {
        const int c = col0 + wn * 64 + nf * 16 + lrow;
        dsv[nf] = colS[c];
        bbv[nf] = bias[c];
      }
#pragma unroll
      for (int i = 0; i < 4; ++i) {
        unsigned int pk = 0;
#pragma unroll
        for (int nf = 0; nf < 4; ++nf) {
          const float v = fmaf((float)acc[mf][nf][i], rs4[i] * dsv[nf], bbv[nf]);
          const float g = gelu_f(v);
          const unsigned int b = (unsigned int)(unsigned char)(char)q8i(g, IH1S);
          pk |= b << (8 * nf);
        }
        *(unsigned int*)&outQ[(size_t)(r0 + i) * N + kbase] = pk;
      }
    }
    return;
  }

  // EPI == 5 : 2-pass LDS bounce (128c x 128t f32, stride 132) -> coalesced stores
  float* fb = (float*)lds;
  const int bidx = row0 >> 12;
  const int t0 = row0 & 4095;
#pragma unroll
  for (int p = 0; p < 2; ++p) {
    if ((wn >> 1) == p) {
#pragma unroll
      for (int mf = 0; mf < 4; ++mf) {
        const int tl = wm * 64 + mf * 16 + lg * 4;
#pragma unroll
        for (int nf = 0; nf < 4; ++nf) {
          const int cl = (wn & 1) * 64 + nf * 16 + lrow;
          const int c = col0 + p * 128 + cl;
          const float ds = H1S * colS[c];
          const float bb = bias[c];
          f32x4 v;
#pragma unroll
          for (int i = 0; i < 4; ++i) v[i] = fmaf((float)acc[mf][nf][i], ds, bb);
          *(f32x4*)&fb[cl * 132 + tl] = v;
        }
      }
    }
    __syncthreads();
#pragma unroll
    for (int j = 0; j < 8; ++j) {
      const int cl = j * 16 + w * 2 + (lane >> 5);
      const int t = (lane & 31) * 4;
      const f32x4 v = *(const f32x4*)&fb[cl * 132 + t];
      const size_t addr = ((size_t)(bidx * C_ + col0 + p * 128 + cl)) * T_ + t0 + t;
      const us4 rv = *(const us4*)&resU[addr];
      f32x4 o;
#pragma unroll
      for (int i = 0; i < 4; ++i) o[i] = v[i] + bf2f(rv[i]);
      *(f32x4*)&outF[addr] = o;
    }
    __syncthreads();
  }
}

// ---------------- fused conv1d(k=7,p=3) + AdaLayerNorm -> int8 yln + per-token scale --------

__global__ __launch_bounds__(256) void convq_kernel(
    const unsigned short* __restrict__ rs,
    const float* __restrict__ dww,
    const float* __restrict__ dwb,
    const int* __restrict__ ids,
    const float* __restrict__ sce,
    const float* __restrict__ she,
    char* __restrict__ ylnq,
    float* __restrict__ yscale) {
  __shared__ unsigned short rbuf[512 * 28];   // [c][16t window + pad]
  __shared__ float cbuf[8 * 520];
  const int tid = threadIdx.x;
  const int t0 = blockIdx.x * 8;
  const int b = blockIdx.y;
  const int w0 = t0 - 4;                      // window [w0, w0+16)
#pragma unroll
  for (int s = 0; s < 8; ++s) {
    const int f = s * 256 + tid;
    const int c = f >> 2, j = f & 3;
    const int t = w0 + j * 4;
    us4 v = {0, 0, 0, 0};
    if (t >= 0 && t + 3 < T_) {
      v = *(const us4*)&rs[((size_t)(b * C_ + c)) * T_ + t];
    } else {
#pragma unroll
      for (int e = 0; e < 4; ++e)
        if (t + e >= 0 && t + e < T_) v[e] = rs[((size_t)(b * C_ + c)) * T_ + t + e];
    }
    *(us4*)&rbuf[c * 28 + j * 4] = v;
  }
  __syncthreads();
#pragma unroll
  for (int cc = 0; cc < 2; ++cc) {
    const int c = cc * 256 + tid;
    float f[15];
#pragma unroll
    for (int i = 0; i < 15; ++i) f[i] = bf2f(rbuf[c * 28 + i]);
    float wk[7];
#pragma unroll
    for (int k = 0; k < 7; ++k) wk[k] = dww[c * 7 + k];
    const float bb = dwb[c];
#pragma unroll
    for (int tt = 0; tt < 8; ++tt) {
      float s = bb;
#pragma unroll
      for (int k = 0; k < 7; ++k) s += f[tt + 1 + k] * wk[k];
      cbuf[tt * 520 + c] = s;
    }
  }
  __syncthreads();
  const int lane = tid & 63, w = tid >> 6;
  const int id = ids[b];
#pragma unroll
  for (int tt = 0; tt < 2; ++tt) {
    const int t = w * 2 + tt;
    const f32x4 v0 = *(const f32x4*)&cbuf[t * 520 + lane * 8];
    const f32x4 v1 = *(const f32x4*)&cbuf[t * 520 + lane * 8 + 4];
    float s = 0.f, sq = 0.f;
#pragma unroll
    for (int i = 0; i < 4; ++i) { s += v0[i]; sq += v0[i] * v0[i]; }
#pragma unroll
    for (int i = 0; i < 4; ++i) { s += v1[i]; sq += v1[i] * v1[i]; }
#pragma unroll
    for (int off = 1; off < 64; off <<= 1) {
      s += __shfl_xor(s, off);
      sq += __shfl_xor(sq, off);
    }
    const float mean = s * (1.0f / 512.0f);
    const float var = sq * (1.0f / 512.0f) - mean * mean;
    const float rstd = rsqrtf(var + 1e-6f);
    const f32x4 sc0 = *(const f32x4*)&sce[id * C_ + lane * 8];
    const f32x4 sc1 = *(const f32x4*)&sce[id * C_ + lane * 8 + 4];
    const f32x4 sh0 = *(const f32x4*)&she[id * C_ + lane * 8];
    const f32x4 sh1 = *(const f32x4*)&she[id * C_ + lane * 8 + 4];
    float y[8];
    float amax = 0.f;
#pragma unroll
    for (int i = 0; i < 4; ++i) {
      y[i]     = (v0[i] - mean) * rstd * sc0[i] + sh0[i];
      y[4 + i] = (v1[i] - mean) * rstd * sc1[i] + sh1[i];
    }
#pragma unroll
    for (int i = 0; i < 8; ++i) amax = fmaxf(amax, fabsf(y[i]));
#pragma unroll
    for (int off = 1; off < 64; off <<= 1) amax = fmaxf(amax, __shfl_xor(amax, off));
    amax = fmaxf(amax, 1e-20f);
    const float inv = 127.0f / amax;
    const int tg = b * T_ + t0 + t;
    char8v o;
#pragma unroll
    for (int i = 0; i < 8; ++i) o[i] = q8(y[i], inv);
    *(char8v*)&ylnq[(size_t)tg * C_ + lane * 8] = o;
    if (lane == 0) yscale[tg] = amax * (1.0f / 127.0f);
  }
}

// ---------------- launch ----------------

extern "C" void kernel_launch(void* const* d_in, const int* in_sizes, int n_in,
                              void* d_out, int out_size, void* d_ws, size_t ws_size,
                              hipStream_t stream) {
  const float* x   = (const float*)d_in[0];
  const int*   ids = (const int*)d_in[1];
  const float* Wq  = (const float*)d_in[2];
  const float* bq  = (const float*)d_in[3];
  const float* Wkv = (const float*)d_in[4];
  const float* bkv = (const float*)d_in[5];
  const float* Wo  = (const float*)d_in[6];
  const float* bo  = (const float*)d_in[7];
  const float* dww = (const float*)d_in[8];
  const float* dwb = (const float*)d_in[9];
  const float* sce = (const float*)d_in[10];
  const float* she = (const float*)d_in[11];
  const float* W1  = (const float*)d_in[12];
  const float* b1  = (const float*)d_in[13];
  const float* W2  = (const float*)d_in[14];
  const float* b2  = (const float*)d_in[15];
  const float* aux = (const float*)d_in[16];
  float* out = (float*)d_out;

  char* ws = (char*)d_ws;
  unsigned short* xt   = (unsigned short*)(ws + 0);              // 64 MB
  unsigned short* P    = (unsigned short*)(ws + (64u  << 20));   // 64 MB
  char*           ylnq = (char*)(ws + (64u << 20));              // 32 MB (overlays P; P dead)
  float*          ysc  = (float*)(ws + (100u << 20));            // 256 KB
  unsigned short* rs   = (unsigned short*)(ws + (128u << 20));   // 64 MB (bf16)
  char*           H1Q  = (char*)(ws + (192u << 20));             // 96 MB (i8)
  char* sm = ws + (384u << 20);
  float*          kv   = (float*)(sm);                           // 256 KB
  float*          cb   = (float*)(sm + 262144);                  // 2 KB
  unsigned short* MT   = (unsigned short*)(sm + 264192);         // 512 KB
  unsigned short* VoT  = (unsigned short*)(sm + 788480);         // 512 KB
  char*           W1Q  = (char*)(sm + 1312768);                  // 768 KB
  char*           W2Q  = (char*)(sm + 2099200);                  // 768 KB
  float*          w1s  = (float*)(sm + 2885632);                 // 6 KB
  float*          w2s  = (float*)(sm + 2891776);                 // 2 KB

  pre_a<<<dim3(2304), dim3(256), 0, stream>>>(aux, Wkv, bkv, W1, W2, kv, w1s, w2s);
  pre_b<<<dim3(1024), dim3(256), 0, stream>>>(Wq, bq, Wo, kv, MT, cb, VoT);
  pre_w<<<dim3(192),  dim3(256), 0, stream>>>(W1, W2, w1s, w2s, W1Q, W2Q);
  xt_kernel<<<dim3(64, 8, 16), dim3(256), 0, stream>>>(x, xt);

  // attention as two BK=64 m97-structure GEMMs with packed/bounced epilogues
  gemm_mfma<512, 512, 4, 1><<<dim3(2048), dim3(256), 0, stream>>>(
      xt, MT, cb, P, nullptr, nullptr);
  gemm_mfma<512, 512, 4, 4><<<dim3(2048), dim3(256), 0, stream>>>(
      P, VoT, bo, rs, xt, nullptr);
  convq_kernel<<<dim3(512, 16), dim3(256), 0, stream>>>(rs, dww, dwb, ids, sce, she,
                                                        ylnq, ysc);
  // MLP as two int8 8-wave GEMMs, coalesced staging + swizzled LDS chunks
  gemm8w<1536, 512, 6, 3><<<dim3(3072), dim3(512), 0, stream>>>(
      ylnq, W1Q, ysc, w1s, b1, H1Q, nullptr, nullptr);
  gemm8w<512, 1536, 2, 5><<<dim3(1024), dim3(512), 0, stream>>>(
      H1Q, W2Q, nullptr, w2s, b2, nullptr, rs, out);
}